// Round 1
// baseline (5805.376 us; speedup 1.0000x reference)
//
#include <hip/hip_runtime.h>
#include <math.h>

#define B_   64
#define T_   2048
#define HID_ 128
#define G3_  384   // 3*HID
#define IN_  128
#define E_   64

__device__ __forceinline__ float rcp_(float x)     { return __builtin_amdgcn_rcpf(x); }
__device__ __forceinline__ float sigmoid_(float x) { return rcp_(1.f + __expf(-x)); }
__device__ __forceinline__ float tanh_(float x)    { return 1.f - 2.f * rcp_(1.f + __expf(2.f * x)); }

// Kernel 0: gi[t][b][g] = x[b][t][:] . w_ih[g][:] + b_ih[g], for t in [t0,t1)
// One block = one batch b x 32 timesteps. 384 threads, thread = one gate row g.
// w_ih row held in 32 float4 VGPRs; x rows staged in LDS, read wave-uniform (broadcast).
__global__ __launch_bounds__(384)
void gi_kernel(const float* __restrict__ x, const float* __restrict__ w_ih,
               const float* __restrict__ b_ih, float* __restrict__ gi,
               int t0, int t1, int nT32)
{
    const int tid = threadIdx.x;
    const int b  = blockIdx.x / nT32;
    const int tc = blockIdx.x % nT32;
    const int tstart = t0 + tc * 32;
    int rows = t1 - tstart; if (rows > 32) rows = 32;
    if (rows <= 0) return;

    __shared__ float x_sh[32 * IN_];
    const float4* xsrc = reinterpret_cast<const float4*>(x + ((size_t)b * T_ + tstart) * IN_);
    float4* xdst = reinterpret_cast<float4*>(x_sh);
    const int n4 = rows * (IN_ / 4);
    for (int i = tid; i < n4; i += 384) xdst[i] = xsrc[i];

    float4 w4[32];
    const float4* wsrc = reinterpret_cast<const float4*>(w_ih + (size_t)tid * IN_);
    #pragma unroll
    for (int i = 0; i < 32; i++) w4[i] = wsrc[i];
    const float bih = b_ih[tid];
    __syncthreads();

    for (int r = 0; r < rows; r++) {
        const float4* xp = reinterpret_cast<const float4*>(x_sh + r * IN_);
        float a0 = 0.f, a1 = 0.f, a2 = 0.f, a3 = 0.f;
        #pragma unroll
        for (int k = 0; k < 32; k++) {
            float4 xv = xp[k];  // wave-uniform address -> LDS broadcast, conflict-free
            a0 = fmaf(w4[k].x, xv.x, a0);
            a1 = fmaf(w4[k].y, xv.y, a1);
            a2 = fmaf(w4[k].z, xv.z, a2);
            a3 = fmaf(w4[k].w, xv.w, a3);
        }
        gi[(size_t)(tstart - t0 + r) * B_ * G3_ + (size_t)b * G3_ + tid] = (a0 + a1) + (a2 + a3) + bih;
    }
}

// Kernel 1: the GRU recurrence for t in [t0,t1). One block per batch element.
// 384 threads: thread g owns w_hh row g in 32 float4 VGPRs.
//   g in [0,128): r-gate   g in [128,256): z-gate   g in [256,384): n pre-activation + h update
// h lives in LDS; broadcast-read (wave-uniform ds_read_b128). gi prefetched 4 steps ahead.
// state layout in ws (after gi buffer): h[B][HID] then hsum[B][HID]  (used only when chunked)
__global__ __launch_bounds__(384)
void rec_kernel(const float* __restrict__ gi, const float* __restrict__ w_hh,
                const float* __restrict__ b_hh,
                const float* __restrict__ w_proj, const float* __restrict__ b_proj,
                float* __restrict__ out, float* __restrict__ state,
                int t0, int t1)
{
    const int tid = threadIdx.x;
    const int b = blockIdx.x;
    const int nT = t1 - t0;   // guaranteed multiple of 4, >= 4

    __shared__ float h_sh[HID_];
    __shared__ float gate_sh[256];

    float4 w4[32];
    const float4* wsrc = reinterpret_cast<const float4*>(w_hh + (size_t)tid * HID_);
    #pragma unroll
    for (int i = 0; i < 32; i++) w4[i] = wsrc[i];
    const float bhh = b_hh[tid];

    float hsum = 0.f;
    if (tid < HID_) h_sh[tid] = (t0 == 0) ? 0.f : state[b * HID_ + tid];
    if (t0 != 0 && tid >= 256) hsum = state[B_ * HID_ + b * HID_ + (tid - 256)];
    __syncthreads();

    const float* gib = gi + (size_t)b * G3_ + tid;
    const size_t stepStride = (size_t)B_ * G3_;

    float cur[4], nxt[4];
    #pragma unroll
    for (int i = 0; i < 4; i++) cur[i] = gib[stepStride * (size_t)i];

    for (int tg = 0; tg < nT; tg += 4) {
        // prefetch next group of 4 timesteps (clamped at the end)
        #pragma unroll
        for (int i = 0; i < 4; i++) {
            int tn = tg + 4 + i; if (tn > nT - 1) tn = nT - 1;
            nxt[i] = gib[stepStride * (size_t)tn];
        }
        #pragma unroll
        for (int i = 0; i < 4; i++) {
            // gh_g = w_hh[g] . h  (+ b_hh[g])
            const float4* hp = reinterpret_cast<const float4*>(h_sh);
            float a0 = 0.f, a1 = 0.f, a2 = 0.f, a3 = 0.f;
            #pragma unroll
            for (int k = 0; k < 32; k++) {
                float4 hv = hp[k];  // wave-uniform -> broadcast
                a0 = fmaf(w4[k].x, hv.x, a0);
                a1 = fmaf(w4[k].y, hv.y, a1);
                a2 = fmaf(w4[k].z, hv.z, a2);
                a3 = fmaf(w4[k].w, hv.w, a3);
            }
            const float hdot = (a0 + a1) + (a2 + a3) + bhh;
            const float giv = cur[i];
            float hn_reg = 0.f;
            if (tid < 256) {
                gate_sh[tid] = sigmoid_(giv + hdot);   // r (g<128) and z (128<=g<256)
            } else {
                hn_reg = hdot;                          // h_n (includes b_hh)
            }
            __syncthreads();
            if (tid >= 256) {
                const int jj = tid - 256;
                const float r = gate_sh[jj];
                const float z = gate_sh[128 + jj];
                const float n = tanh_(giv + r * hn_reg);
                const float hprev = h_sh[jj];
                const float hnew = (1.f - z) * n + z * hprev;
                h_sh[jj] = hnew;
                hsum += hnew;
            }
            __syncthreads();
        }
        #pragma unroll
        for (int i = 0; i < 4; i++) cur[i] = nxt[i];
    }

    if (t1 < T_) {
        if (tid < HID_)  state[b * HID_ + tid] = h_sh[tid];
        if (tid >= 256)  state[B_ * HID_ + b * HID_ + (tid - 256)] = hsum;
    } else {
        // epilogue: mean-pool + projection  out[b][e] = pooled . w_proj[e] + b_proj[e]
        if (tid >= 256) gate_sh[tid - 256] = hsum * (1.f / (float)T_);
        __syncthreads();
        if (tid < E_) {
            const float4* wp = reinterpret_cast<const float4*>(w_proj + (size_t)tid * HID_);
            const float4* pp = reinterpret_cast<const float4*>(gate_sh);
            float a0 = 0.f, a1 = 0.f, a2 = 0.f, a3 = 0.f;
            #pragma unroll
            for (int k = 0; k < 32; k++) {
                float4 wv = wp[k]; float4 pv = pp[k];
                a0 = fmaf(wv.x, pv.x, a0);
                a1 = fmaf(wv.y, pv.y, a1);
                a2 = fmaf(wv.z, pv.z, a2);
                a3 = fmaf(wv.w, pv.w, a3);
            }
            out[b * E_ + tid] = (a0 + a1) + (a2 + a3) + b_proj[tid];
        }
    }
}

extern "C" void kernel_launch(void* const* d_in, const int* in_sizes, int n_in,
                              void* d_out, int out_size, void* d_ws, size_t ws_size,
                              hipStream_t stream)
{
    const float* x      = (const float*)d_in[0];
    const float* w_ih   = (const float*)d_in[1];
    const float* w_hh   = (const float*)d_in[2];
    const float* b_ih   = (const float*)d_in[3];
    const float* b_hh   = (const float*)d_in[4];
    const float* w_proj = (const float*)d_in[5];
    const float* b_proj = (const float*)d_in[6];
    float* out = (float*)d_out;

    // ws layout: [ gi chunk buffer: chunkT * B * 3H * f32 ][ state: h + hsum, 64 KB ]
    const size_t state_bytes = (size_t)2 * B_ * HID_ * sizeof(float);
    const size_t per_t = (size_t)B_ * G3_ * sizeof(float);   // 98304 B per timestep
    size_t avail = ws_size > state_bytes ? ws_size - state_bytes : 0;
    int chunkT = (int)(avail / per_t);
    if (chunkT > T_) chunkT = T_;
    chunkT &= ~3;                 // multiple of 4 (keeps every chunk length %4 == 0)
    if (chunkT < 4) chunkT = 4;   // minimum viable; assumes ws >= ~460 KB

    float* gi_buf = (float*)d_ws;
    float* state  = (float*)((char*)d_ws + (size_t)chunkT * per_t);

    for (int t0 = 0; t0 < T_; t0 += chunkT) {
        int t1 = t0 + chunkT; if (t1 > T_) t1 = T_;
        int nT = t1 - t0;
        int nT32 = (nT + 31) / 32;
        gi_kernel<<<dim3(B_ * nT32), dim3(384), 0, stream>>>(x, w_ih, b_ih, gi_buf, t0, t1, nT32);
        rec_kernel<<<dim3(B_), dim3(384), 0, stream>>>(gi_buf, w_hh, b_hh, w_proj, b_proj,
                                                       out, state, t0, t1);
    }
}

// Round 2
// 3581.181 us; speedup vs baseline: 1.6211x; 1.6211x over previous
//
#include <hip/hip_runtime.h>
#include <math.h>

#define B_   64
#define T_   2048
#define HID_ 128
#define G3_  384   // 3*HID
#define IN_  128
#define E_   64

#define TS_  128   // t-tile of gi GEMM
#define GS_  128   // g-tile
#define KS_  32    // K stage

__device__ __forceinline__ float rcp_(float x)     { return __builtin_amdgcn_rcpf(x); }
__device__ __forceinline__ float sigmoid_(float x) { return rcp_(1.f + __expf(-x)); }
__device__ __forceinline__ float tanh_(float x)    { return 1.f - 2.f * rcp_(1.f + __expf(2.f * x)); }

// ---------------------------------------------------------------------------
// gi GEMM: gi[tl][b][g] = x[b][t0+tl][:] . w_ih[g][:] + b_ih[g]
// Per block: one (b, 128-t tile, 128-g tile). 256 threads, 8x8 outputs each.
// K=128 staged through LDS in 4 chunks of 32, A and B stored k-major for
// b128 fragment reads. Bank analysis: A-read addr k*128+8*ty (ty 0..3/wave,
// banks 8ty -> distinct); B-read addr k*128+4*tx (tx 0..15 -> 2-way, free).
// ---------------------------------------------------------------------------
__global__ __launch_bounds__(256)
void gi_gemm(const float* __restrict__ x, const float* __restrict__ w_ih,
             const float* __restrict__ b_ih, float* __restrict__ gi, int t0)
{
    __shared__ float Ash[KS_][TS_];   // [k][t]
    __shared__ float Bsh[KS_][GS_];   // [k][g]

    const int tid = threadIdx.x;
    const int gt  = blockIdx.x;            // 0..2
    const int tt  = blockIdx.y;            // t-tile within chunk
    const int b   = blockIdx.z;            // 0..63
    const int gbase  = gt * GS_;
    const int tlocal = tt * TS_;           // t relative to chunk start
    const int tabs   = t0 + tlocal;        // absolute t

    const int tx = tid & 15;               // g-group: cols 4*tx..+3 and 64+4*tx..+3
    const int ty = tid >> 4;               // t-group: rows 8*ty..+7

    const float* xrow = x    + ((size_t)b * T_ + tabs) * IN_;
    const float* wrow = w_ih + (size_t)gbase * IN_;

    float acc[8][8];
    #pragma unroll
    for (int i = 0; i < 8; i++)
        #pragma unroll
        for (int j = 0; j < 8; j++) acc[i][j] = 0.f;

    for (int ks = 0; ks < IN_; ks += KS_) {
        __syncthreads();   // protect previous stage's reads
        // stage A (x) and B (w_ih): 1024 float4 each; idx -> row idx>>3, kgrp idx&7
        #pragma unroll
        for (int i = 0; i < 4; i++) {
            const int idx = tid + i * 256;
            const int r   = idx >> 3;        // t (or g) row 0..127
            const int kg  = idx & 7;         // k-group of 4
            float4 av = *reinterpret_cast<const float4*>(xrow + (size_t)r * IN_ + ks + kg * 4);
            Ash[kg * 4 + 0][r] = av.x;
            Ash[kg * 4 + 1][r] = av.y;
            Ash[kg * 4 + 2][r] = av.z;
            Ash[kg * 4 + 3][r] = av.w;
            float4 bv = *reinterpret_cast<const float4*>(wrow + (size_t)r * IN_ + ks + kg * 4);
            Bsh[kg * 4 + 0][r] = bv.x;
            Bsh[kg * 4 + 1][r] = bv.y;
            Bsh[kg * 4 + 2][r] = bv.z;
            Bsh[kg * 4 + 3][r] = bv.w;
        }
        __syncthreads();

        #pragma unroll
        for (int k = 0; k < KS_; k++) {
            float4 a0 = *reinterpret_cast<const float4*>(&Ash[k][ty * 8]);
            float4 a1 = *reinterpret_cast<const float4*>(&Ash[k][ty * 8 + 4]);
            float4 b0 = *reinterpret_cast<const float4*>(&Bsh[k][tx * 4]);
            float4 b1 = *reinterpret_cast<const float4*>(&Bsh[k][64 + tx * 4]);
            const float av[8] = {a0.x,a0.y,a0.z,a0.w,a1.x,a1.y,a1.z,a1.w};
            const float bv[8] = {b0.x,b0.y,b0.z,b0.w,b1.x,b1.y,b1.z,b1.w};
            #pragma unroll
            for (int i = 0; i < 8; i++)
                #pragma unroll
                for (int j = 0; j < 8; j++)
                    acc[i][j] = fmaf(av[i], bv[j], acc[i][j]);
        }
    }

    float bi[8];
    #pragma unroll
    for (int c = 0; c < 4; c++) {
        bi[c]     = b_ih[gbase + tx * 4 + c];
        bi[4 + c] = b_ih[gbase + 64 + tx * 4 + c];
    }

    #pragma unroll
    for (int i = 0; i < 8; i++) {
        const size_t o = (size_t)(tlocal + ty * 8 + i) * (B_ * G3_) + (size_t)b * G3_ + gbase;
        float4 v0 = { acc[i][0] + bi[0], acc[i][1] + bi[1], acc[i][2] + bi[2], acc[i][3] + bi[3] };
        float4 v1 = { acc[i][4] + bi[4], acc[i][5] + bi[5], acc[i][6] + bi[6], acc[i][7] + bi[7] };
        *reinterpret_cast<float4*>(gi + o + tx * 4)      = v0;
        *reinterpret_cast<float4*>(gi + o + 64 + tx * 4) = v1;
    }
}

// ---------------------------------------------------------------------------
// GRU recurrence. One block of 128 threads per batch element.
// Thread j owns gate rows j (r), 128+j (z), 256+j (n): all three dots plus the
// h-update happen in-thread -> no gate exchange, one barrier per step.
// w_hh rows held in 96 float4 VGPRs (384 regs -> __launch_bounds__(128,1)).
// h broadcast from double-buffered LDS via wave-uniform ds_read_b128.
// ---------------------------------------------------------------------------
__global__ __launch_bounds__(128, 1)
void rec_kernel(const float* __restrict__ gi, const float* __restrict__ w_hh,
                const float* __restrict__ b_hh,
                const float* __restrict__ w_proj, const float* __restrict__ b_proj,
                float* __restrict__ out, float* __restrict__ state,
                int t0, int t1)
{
    const int j = threadIdx.x;   // 0..127
    const int b = blockIdx.x;
    const int nT = t1 - t0;

    __shared__ float h_sh[2][HID_];
    __shared__ float pooled[HID_];

    float4 wr[32], wz[32], wn[32];
    {
        const float4* r0 = reinterpret_cast<const float4*>(w_hh + (size_t)j * HID_);
        const float4* r1 = reinterpret_cast<const float4*>(w_hh + (size_t)(128 + j) * HID_);
        const float4* r2 = reinterpret_cast<const float4*>(w_hh + (size_t)(256 + j) * HID_);
        #pragma unroll
        for (int k = 0; k < 32; k++) { wr[k] = r0[k]; wz[k] = r1[k]; wn[k] = r2[k]; }
    }
    const float bhr = b_hh[j], bhz = b_hh[128 + j], bhn = b_hh[256 + j];

    float hj, hsum;
    if (t0 == 0) { hj = 0.f; hsum = 0.f; }
    else { hj = state[b * HID_ + j]; hsum = state[B_ * HID_ + b * HID_ + j]; }
    h_sh[0][j] = hj;
    __syncthreads();

    const float* gib = gi + (size_t)b * G3_;
    const size_t S = (size_t)B_ * G3_;

    float gr = gib[j], gz = gib[128 + j], gn = gib[256 + j];

    int p = 0;
    for (int t = 0; t < nT; ++t) {
        // prefetch next step's gi (1 step ahead ~ load latency)
        const float* gnx = gib + (size_t)(t + 1 < nT ? t + 1 : t) * S;
        const float gr2 = gnx[j], gz2 = gnx[128 + j], gn2 = gnx[256 + j];

        const float4* hp = reinterpret_cast<const float4*>(h_sh[p]);
        float4 ar = {0.f,0.f,0.f,0.f}, az = {0.f,0.f,0.f,0.f}, an = {0.f,0.f,0.f,0.f};
        #pragma unroll
        for (int k = 0; k < 32; k++) {
            const float4 hv = hp[k];      // wave-uniform -> LDS broadcast
            ar.x = fmaf(wr[k].x, hv.x, ar.x); ar.y = fmaf(wr[k].y, hv.y, ar.y);
            ar.z = fmaf(wr[k].z, hv.z, ar.z); ar.w = fmaf(wr[k].w, hv.w, ar.w);
            az.x = fmaf(wz[k].x, hv.x, az.x); az.y = fmaf(wz[k].y, hv.y, az.y);
            az.z = fmaf(wz[k].z, hv.z, az.z); az.w = fmaf(wz[k].w, hv.w, az.w);
            an.x = fmaf(wn[k].x, hv.x, an.x); an.y = fmaf(wn[k].y, hv.y, an.y);
            an.z = fmaf(wn[k].z, hv.z, an.z); an.w = fmaf(wn[k].w, hv.w, an.w);
        }
        const float dr = (ar.x + ar.y) + (ar.z + ar.w) + bhr;
        const float dz = (az.x + az.y) + (az.z + az.w) + bhz;
        const float dn = (an.x + an.y) + (an.z + an.w) + bhn;

        const float r = sigmoid_(gr + dr);
        const float z = sigmoid_(gz + dz);
        const float n = tanh_(gn + r * dn);
        const float hnew = (1.f - z) * n + z * hj;
        hj = hnew;
        hsum += hnew;
        h_sh[p ^ 1][j] = hnew;
        __syncthreads();
        p ^= 1;
        gr = gr2; gz = gz2; gn = gn2;
    }

    if (t1 < T_) {
        state[b * HID_ + j] = hj;
        state[B_ * HID_ + b * HID_ + j] = hsum;
    } else {
        pooled[j] = hsum * (1.f / (float)T_);
        __syncthreads();
        if (j < E_) {
            const float4* wp = reinterpret_cast<const float4*>(w_proj + (size_t)j * HID_);
            const float4* pp = reinterpret_cast<const float4*>(pooled);
            float a0 = 0.f, a1 = 0.f, a2 = 0.f, a3 = 0.f;
            #pragma unroll
            for (int k = 0; k < 32; k++) {
                float4 wv = wp[k]; float4 pv = pp[k];
                a0 = fmaf(wv.x, pv.x, a0);
                a1 = fmaf(wv.y, pv.y, a1);
                a2 = fmaf(wv.z, pv.z, a2);
                a3 = fmaf(wv.w, pv.w, a3);
            }
            out[b * E_ + j] = (a0 + a1) + (a2 + a3) + b_proj[j];
        }
    }
}

extern "C" void kernel_launch(void* const* d_in, const int* in_sizes, int n_in,
                              void* d_out, int out_size, void* d_ws, size_t ws_size,
                              hipStream_t stream)
{
    const float* x      = (const float*)d_in[0];
    const float* w_ih   = (const float*)d_in[1];
    const float* w_hh   = (const float*)d_in[2];
    const float* b_ih   = (const float*)d_in[3];
    const float* b_hh   = (const float*)d_in[4];
    const float* w_proj = (const float*)d_in[5];
    const float* b_proj = (const float*)d_in[6];
    float* out = (float*)d_out;

    // ws layout: [ gi chunk buffer: chunkT * B * 3H * f32 ][ state: h + hsum ]
    const size_t state_bytes = (size_t)2 * B_ * HID_ * sizeof(float);
    const size_t per_t = (size_t)B_ * G3_ * sizeof(float);   // 98304 B per timestep
    size_t avail = ws_size > state_bytes ? ws_size - state_bytes : 0;
    int chunkT = (int)(avail / per_t);
    if (chunkT > T_) chunkT = T_;
    chunkT &= ~(TS_ - 1);            // multiple of 128 (gi tile)
    if (chunkT < TS_) chunkT = TS_;  // round 1 evidence: ws >= 201 MB, this won't bind

    float* gi_buf = (float*)d_ws;
    float* state  = (float*)((char*)d_ws + (size_t)chunkT * per_t);

    for (int t0 = 0; t0 < T_; t0 += chunkT) {
        int t1 = t0 + chunkT; if (t1 > T_) t1 = T_;
        int nT = t1 - t0;
        gi_gemm<<<dim3(3, nT / TS_, B_), dim3(256), 0, stream>>>(x, w_ih, b_ih, gi_buf, t0);
        rec_kernel<<<dim3(B_), dim3(128), 0, stream>>>(gi_buf, w_hh, b_hh, w_proj, b_proj,
                                                       out, state, t0, t1);
    }
}

// Round 3
// 1470.984 us; speedup vs baseline: 3.9466x; 2.4345x over previous
//
#include <hip/hip_runtime.h>
#include <math.h>

#define B_   64
#define T_   2048
#define HID_ 128
#define G3_  384   // 3*HID
#define IN_  128
#define E_   64

#define TS_  128   // t-tile of gi GEMM
#define GS_  128   // g-tile
#define KS_  32    // K stage

__device__ __forceinline__ float rcp_(float x)     { return __builtin_amdgcn_rcpf(x); }
__device__ __forceinline__ float sigmoid_(float x) { return rcp_(1.f + __expf(-x)); }
__device__ __forceinline__ float tanh_(float x)    { return 1.f - 2.f * rcp_(1.f + __expf(2.f * x)); }

// quad_perm DPP butterfly adds (VALU pipe, no LDS traffic)
__device__ __forceinline__ float dpp_add_xor1(float x) {
    int v = __builtin_amdgcn_mov_dpp(__float_as_int(x), 0xB1, 0xF, 0xF, true); // [1,0,3,2]
    return x + __int_as_float(v);
}
__device__ __forceinline__ float dpp_add_xor2(float x) {
    int v = __builtin_amdgcn_mov_dpp(__float_as_int(x), 0x4E, 0xF, 0xF, true); // [2,3,0,1]
    return x + __int_as_float(v);
}

// ---------------------------------------------------------------------------
// gi GEMM: gi[tl][b][g] = x[b][t0+tl][:] . w_ih[g][:] + bias[g]
// bias[g] = b_ih[g] + b_hh[g] for g<256 (r,z gates: b_hh enters additively
// pre-sigmoid, so it folds here); b_ih[g] alone for n rows (b_hh_n is
// multiplied by r inside the recurrence).
// ---------------------------------------------------------------------------
__global__ __launch_bounds__(256)
void gi_gemm(const float* __restrict__ x, const float* __restrict__ w_ih,
             const float* __restrict__ b_ih, const float* __restrict__ b_hh,
             float* __restrict__ gi, int t0)
{
    __shared__ float Ash[KS_][TS_];   // [k][t]
    __shared__ float Bsh[KS_][GS_];   // [k][g]

    const int tid = threadIdx.x;
    const int gt  = blockIdx.x;            // 0..2
    const int tt  = blockIdx.y;            // t-tile within chunk
    const int b   = blockIdx.z;            // 0..63
    const int gbase  = gt * GS_;
    const int tlocal = tt * TS_;
    const int tabs   = t0 + tlocal;

    const int tx = tid & 15;
    const int ty = tid >> 4;

    const float* xrow = x    + ((size_t)b * T_ + tabs) * IN_;
    const float* wrow = w_ih + (size_t)gbase * IN_;

    float acc[8][8];
    #pragma unroll
    for (int i = 0; i < 8; i++)
        #pragma unroll
        for (int j = 0; j < 8; j++) acc[i][j] = 0.f;

    for (int ks = 0; ks < IN_; ks += KS_) {
        __syncthreads();
        #pragma unroll
        for (int i = 0; i < 4; i++) {
            const int idx = tid + i * 256;
            const int r   = idx >> 3;
            const int kg  = idx & 7;
            float4 av = *reinterpret_cast<const float4*>(xrow + (size_t)r * IN_ + ks + kg * 4);
            Ash[kg * 4 + 0][r] = av.x;
            Ash[kg * 4 + 1][r] = av.y;
            Ash[kg * 4 + 2][r] = av.z;
            Ash[kg * 4 + 3][r] = av.w;
            float4 bv = *reinterpret_cast<const float4*>(wrow + (size_t)r * IN_ + ks + kg * 4);
            Bsh[kg * 4 + 0][r] = bv.x;
            Bsh[kg * 4 + 1][r] = bv.y;
            Bsh[kg * 4 + 2][r] = bv.z;
            Bsh[kg * 4 + 3][r] = bv.w;
        }
        __syncthreads();

        #pragma unroll
        for (int k = 0; k < KS_; k++) {
            float4 a0 = *reinterpret_cast<const float4*>(&Ash[k][ty * 8]);
            float4 a1 = *reinterpret_cast<const float4*>(&Ash[k][ty * 8 + 4]);
            float4 b0 = *reinterpret_cast<const float4*>(&Bsh[k][tx * 4]);
            float4 b1 = *reinterpret_cast<const float4*>(&Bsh[k][64 + tx * 4]);
            const float av[8] = {a0.x,a0.y,a0.z,a0.w,a1.x,a1.y,a1.z,a1.w};
            const float bv[8] = {b0.x,b0.y,b0.z,b0.w,b1.x,b1.y,b1.z,b1.w};
            #pragma unroll
            for (int i = 0; i < 8; i++)
                #pragma unroll
                for (int j = 0; j < 8; j++)
                    acc[i][j] = fmaf(av[i], bv[j], acc[i][j]);
        }
    }

    float bi[8];
    #pragma unroll
    for (int c = 0; c < 4; c++) {
        const int col0 = gbase + tx * 4 + c;
        const int col1 = gbase + 64 + tx * 4 + c;
        bi[c]     = b_ih[col0] + (col0 < 256 ? b_hh[col0] : 0.f);
        bi[4 + c] = b_ih[col1] + (col1 < 256 ? b_hh[col1] : 0.f);
    }

    #pragma unroll
    for (int i = 0; i < 8; i++) {
        const size_t o = (size_t)(tlocal + ty * 8 + i) * (B_ * G3_) + (size_t)b * G3_ + gbase;
        float4 v0 = { acc[i][0] + bi[0], acc[i][1] + bi[1], acc[i][2] + bi[2], acc[i][3] + bi[3] };
        float4 v1 = { acc[i][4] + bi[4], acc[i][5] + bi[5], acc[i][6] + bi[6], acc[i][7] + bi[7] };
        *reinterpret_cast<float4*>(gi + o + tx * 4)      = v0;
        *reinterpret_cast<float4*>(gi + o + 64 + tx * 4) = v1;
    }
}

// ---------------------------------------------------------------------------
// GRU recurrence. One block of 256 threads (4 waves) per batch element.
// Thread (g = tid>>2, s = tid&3) owns the k-quarter [32s,32s+32) of the six
// gate rows g+64m (m=0..5)  ->  192 weight VGPRs (fits the 256 arch cap).
// Partial dots reduce over s via DPP quad butterfly; thread then owns full
// r/z/n for h-indices g and g+64 -> gates in-thread, ONE barrier per step.
// h chunks staggered 36 dwords apart in LDS so the 4 address groups hit
// disjoint banks (conflict-free wave reads of 8x b128 per wave).
// ---------------------------------------------------------------------------
#define GRU_STEP(CUR, NXT, TLOAD)                                              \
  {                                                                            \
    const float* gn_ = gib + (size_t)(TLOAD) * S;                              \
    _Pragma("unroll")                                                          \
    for (int m = 0; m < 6; m++) NXT[m] = gn_[g + 64 * m];                      \
    const float4* hp_ = reinterpret_cast<const float4*>(&h_sh[p][36 * s]);     \
    float a_[6] = {0.f, 0.f, 0.f, 0.f, 0.f, 0.f};                              \
    _Pragma("unroll")                                                          \
    for (int i = 0; i < 8; i++) {                                              \
      float4 hv = hp_[i];                                                      \
      _Pragma("unroll")                                                        \
      for (int m = 0; m < 6; m++) a_[m] = fmaf(w4[m][i].x, hv.x, a_[m]);       \
      _Pragma("unroll")                                                        \
      for (int m = 0; m < 6; m++) a_[m] = fmaf(w4[m][i].y, hv.y, a_[m]);       \
      _Pragma("unroll")                                                        \
      for (int m = 0; m < 6; m++) a_[m] = fmaf(w4[m][i].z, hv.z, a_[m]);       \
      _Pragma("unroll")                                                        \
      for (int m = 0; m < 6; m++) a_[m] = fmaf(w4[m][i].w, hv.w, a_[m]);       \
    }                                                                          \
    _Pragma("unroll")                                                          \
    for (int m = 0; m < 6; m++) {                                              \
      a_[m] = dpp_add_xor1(a_[m]);                                             \
      a_[m] = dpp_add_xor2(a_[m]);                                             \
    }                                                                          \
    const float r0 = sigmoid_(CUR[0] + a_[0]);                                 \
    const float r1 = sigmoid_(CUR[1] + a_[1]);                                 \
    const float z0 = sigmoid_(CUR[2] + a_[2]);                                 \
    const float z1 = sigmoid_(CUR[3] + a_[3]);                                 \
    const float n0 = tanh_(CUR[4] + r0 * (a_[4] + bh4));                       \
    const float n1 = tanh_(CUR[5] + r1 * (a_[5] + bh5));                       \
    hj0 = (1.f - z0) * n0 + z0 * hj0;                                          \
    hj1 = (1.f - z1) * n1 + z1 * hj1;                                          \
    hs0 += hj0; hs1 += hj1;                                                    \
    if (s == 0) {                                                              \
      h_sh[p ^ 1][36 * c0 + wi]      = hj0;                                    \
      h_sh[p ^ 1][36 * c0 + 72 + wi] = hj1;                                    \
    }                                                                          \
    __syncthreads();                                                           \
    p ^= 1;                                                                    \
  }

__global__ __launch_bounds__(256, 1)
void rec_kernel(const float* __restrict__ gi, const float* __restrict__ w_hh,
                const float* __restrict__ b_hh,
                const float* __restrict__ w_proj, const float* __restrict__ b_proj,
                float* __restrict__ out, float* __restrict__ state,
                int t0, int t1)
{
    const int tid = threadIdx.x;
    const int b = blockIdx.x;
    const int g = tid >> 2;     // 0..63
    const int s = tid & 3;      // k-quarter
    const int nT = t1 - t0;     // multiple of 128 -> even

    __shared__ float h_sh[2][144];   // 4 chunks of 32, staggered by 36 dwords
    __shared__ float pooled[HID_];

    float4 w4[6][8];
    #pragma unroll
    for (int m = 0; m < 6; m++) {
        const float* wr = w_hh + (size_t)(g + 64 * m) * HID_ + 32 * s;
        #pragma unroll
        for (int i = 0; i < 8; i++) w4[m][i] = reinterpret_cast<const float4*>(wr)[i];
    }
    const float bh4 = b_hh[256 + g];
    const float bh5 = b_hh[320 + g];

    const int c0 = g >> 5, wi = g & 31;
    float hj0, hj1, hs0, hs1;
    if (t0 == 0) { hj0 = hj1 = hs0 = hs1 = 0.f; }
    else {
        hj0 = state[b * HID_ + g];             hj1 = state[b * HID_ + g + 64];
        hs0 = state[B_ * HID_ + b * HID_ + g]; hs1 = state[B_ * HID_ + b * HID_ + g + 64];
    }
    if (tid < HID_) {
        float v = (t0 == 0) ? 0.f : state[b * HID_ + tid];
        h_sh[0][36 * (tid >> 5) + (tid & 31)] = v;
    }
    __syncthreads();

    const float* gib = gi + (size_t)b * G3_;
    const size_t S = (size_t)B_ * G3_;

    float cur[6], nxt[6];
    #pragma unroll
    for (int m = 0; m < 6; m++) cur[m] = gib[g + 64 * m];

    int p = 0;
    for (int t = 0; t < nT; t += 2) {
        GRU_STEP(cur, nxt, t + 1);                            // t+1 < nT (nT even)
        const int tl2 = (t + 2 < nT) ? t + 2 : nT - 1;        // clamped; unused if last
        GRU_STEP(nxt, cur, tl2);
    }

    if (t1 < T_) {
        if (s == 0) {
            state[b * HID_ + g]             = hj0;  state[b * HID_ + g + 64]             = hj1;
            state[B_ * HID_ + b * HID_ + g] = hs0;  state[B_ * HID_ + b * HID_ + g + 64] = hs1;
        }
    } else {
        if (s == 0) {
            pooled[g]      = hs0 * (1.f / (float)T_);
            pooled[g + 64] = hs1 * (1.f / (float)T_);
        }
        __syncthreads();
        if (tid < E_) {
            const float4* wp = reinterpret_cast<const float4*>(w_proj + (size_t)tid * HID_);
            const float4* pp = reinterpret_cast<const float4*>(pooled);
            float a0 = 0.f, a1 = 0.f, a2 = 0.f, a3 = 0.f;
            #pragma unroll
            for (int k = 0; k < 32; k++) {
                float4 wv = wp[k]; float4 pv = pp[k];
                a0 = fmaf(wv.x, pv.x, a0);
                a1 = fmaf(wv.y, pv.y, a1);
                a2 = fmaf(wv.z, pv.z, a2);
                a3 = fmaf(wv.w, pv.w, a3);
            }
            out[b * E_ + tid] = (a0 + a1) + (a2 + a3) + b_proj[tid];
        }
    }
}

extern "C" void kernel_launch(void* const* d_in, const int* in_sizes, int n_in,
                              void* d_out, int out_size, void* d_ws, size_t ws_size,
                              hipStream_t stream)
{
    const float* x      = (const float*)d_in[0];
    const float* w_ih   = (const float*)d_in[1];
    const float* w_hh   = (const float*)d_in[2];
    const float* b_ih   = (const float*)d_in[3];
    const float* b_hh   = (const float*)d_in[4];
    const float* w_proj = (const float*)d_in[5];
    const float* b_proj = (const float*)d_in[6];
    float* out = (float*)d_out;

    // ws layout: [ gi chunk buffer: chunkT * B * 3H * f32 ][ state: h + hsum ]
    const size_t state_bytes = (size_t)2 * B_ * HID_ * sizeof(float);
    const size_t per_t = (size_t)B_ * G3_ * sizeof(float);
    size_t avail = ws_size > state_bytes ? ws_size - state_bytes : 0;
    int chunkT = (int)(avail / per_t);
    if (chunkT > T_) chunkT = T_;
    chunkT &= ~(TS_ - 1);
    if (chunkT < TS_) chunkT = TS_;

    float* gi_buf = (float*)d_ws;
    float* state  = (float*)((char*)d_ws + (size_t)chunkT * per_t);

    for (int t0 = 0; t0 < T_; t0 += chunkT) {
        int t1 = t0 + chunkT; if (t1 > T_) t1 = T_;
        int nT = t1 - t0;
        gi_gemm<<<dim3(3, nT / TS_, B_), dim3(256), 0, stream>>>(x, w_ih, b_ih, b_hh, gi_buf, t0);
        rec_kernel<<<dim3(B_), dim3(256), 0, stream>>>(gi_buf, w_hh, b_hh, w_proj, b_proj,
                                                       out, state, t0, t1);
    }
}

// Round 4
// 1441.248 us; speedup vs baseline: 4.0280x; 1.0206x over previous
//
#include <hip/hip_runtime.h>
#include <math.h>

#define B_   64
#define T_   2048
#define HID_ 128
#define G3_  384   // 3*HID
#define IN_  128
#define E_   64

#define TS_  128   // t-tile of gi GEMM
#define GS_  128   // g-tile
#define KS_  32    // K stage

__device__ __forceinline__ float rcp_(float x)     { return __builtin_amdgcn_rcpf(x); }
__device__ __forceinline__ float sigmoid_(float x) { return rcp_(1.f + __expf(-x)); }
__device__ __forceinline__ float tanh_(float x)    { return 1.f - 2.f * rcp_(1.f + __expf(2.f * x)); }

// DPP reduction stages over the 8-lane s-group (lanes l..l+7, 8-aligned):
//  xor1, xor2 (quad_perm), then row_half_mirror (0x141) exchanges the two
//  quads within each 8-half of a DPP row -> full 8-lane sum in every lane.
__device__ __forceinline__ float dpp_add_xor1(float x) {
    int v = __builtin_amdgcn_mov_dpp(__float_as_int(x), 0xB1, 0xF, 0xF, true); // [1,0,3,2]
    return x + __int_as_float(v);
}
__device__ __forceinline__ float dpp_add_xor2(float x) {
    int v = __builtin_amdgcn_mov_dpp(__float_as_int(x), 0x4E, 0xF, 0xF, true); // [2,3,0,1]
    return x + __int_as_float(v);
}
__device__ __forceinline__ float dpp_add_hmirror(float x) {
    int v = __builtin_amdgcn_mov_dpp(__float_as_int(x), 0x141, 0xF, 0xF, true); // row_half_mirror
    return x + __int_as_float(v);
}

// ---------------------------------------------------------------------------
// gi GEMM: gi[tl][b][g] = x[b][t0+tl][:] . w_ih[g][:] + bias[g]
// bias folds b_hh for the r,z gates (additive pre-sigmoid).
// ---------------------------------------------------------------------------
__global__ __launch_bounds__(256)
void gi_gemm(const float* __restrict__ x, const float* __restrict__ w_ih,
             const float* __restrict__ b_ih, const float* __restrict__ b_hh,
             float* __restrict__ gi, int t0)
{
    __shared__ float Ash[KS_][TS_];   // [k][t]
    __shared__ float Bsh[KS_][GS_];   // [k][g]

    const int tid = threadIdx.x;
    const int gt  = blockIdx.x;
    const int tt  = blockIdx.y;
    const int b   = blockIdx.z;
    const int gbase  = gt * GS_;
    const int tlocal = tt * TS_;
    const int tabs   = t0 + tlocal;

    const int tx = tid & 15;
    const int ty = tid >> 4;

    const float* xrow = x    + ((size_t)b * T_ + tabs) * IN_;
    const float* wrow = w_ih + (size_t)gbase * IN_;

    float acc[8][8];
    #pragma unroll
    for (int i = 0; i < 8; i++)
        #pragma unroll
        for (int j = 0; j < 8; j++) acc[i][j] = 0.f;

    for (int ks = 0; ks < IN_; ks += KS_) {
        __syncthreads();
        #pragma unroll
        for (int i = 0; i < 4; i++) {
            const int idx = tid + i * 256;
            const int r   = idx >> 3;
            const int kg  = idx & 7;
            float4 av = *reinterpret_cast<const float4*>(xrow + (size_t)r * IN_ + ks + kg * 4);
            Ash[kg * 4 + 0][r] = av.x;
            Ash[kg * 4 + 1][r] = av.y;
            Ash[kg * 4 + 2][r] = av.z;
            Ash[kg * 4 + 3][r] = av.w;
            float4 bv = *reinterpret_cast<const float4*>(wrow + (size_t)r * IN_ + ks + kg * 4);
            Bsh[kg * 4 + 0][r] = bv.x;
            Bsh[kg * 4 + 1][r] = bv.y;
            Bsh[kg * 4 + 2][r] = bv.z;
            Bsh[kg * 4 + 3][r] = bv.w;
        }
        __syncthreads();

        #pragma unroll
        for (int k = 0; k < KS_; k++) {
            float4 a0 = *reinterpret_cast<const float4*>(&Ash[k][ty * 8]);
            float4 a1 = *reinterpret_cast<const float4*>(&Ash[k][ty * 8 + 4]);
            float4 b0 = *reinterpret_cast<const float4*>(&Bsh[k][tx * 4]);
            float4 b1 = *reinterpret_cast<const float4*>(&Bsh[k][64 + tx * 4]);
            const float av[8] = {a0.x,a0.y,a0.z,a0.w,a1.x,a1.y,a1.z,a1.w};
            const float bv[8] = {b0.x,b0.y,b0.z,b0.w,b1.x,b1.y,b1.z,b1.w};
            #pragma unroll
            for (int i = 0; i < 8; i++)
                #pragma unroll
                for (int j = 0; j < 8; j++)
                    acc[i][j] = fmaf(av[i], bv[j], acc[i][j]);
        }
    }

    float bi[8];
    #pragma unroll
    for (int c = 0; c < 4; c++) {
        const int col0 = gbase + tx * 4 + c;
        const int col1 = gbase + 64 + tx * 4 + c;
        bi[c]     = b_ih[col0] + (col0 < 256 ? b_hh[col0] : 0.f);
        bi[4 + c] = b_ih[col1] + (col1 < 256 ? b_hh[col1] : 0.f);
    }

    #pragma unroll
    for (int i = 0; i < 8; i++) {
        const size_t o = (size_t)(tlocal + ty * 8 + i) * (B_ * G3_) + (size_t)b * G3_ + gbase;
        float4 v0 = { acc[i][0] + bi[0], acc[i][1] + bi[1], acc[i][2] + bi[2], acc[i][3] + bi[3] };
        float4 v1 = { acc[i][4] + bi[4], acc[i][5] + bi[5], acc[i][6] + bi[6], acc[i][7] + bi[7] };
        *reinterpret_cast<float4*>(gi + o + tx * 4)      = v0;
        *reinterpret_cast<float4*>(gi + o + 64 + tx * 4) = v1;
    }
}

// ---------------------------------------------------------------------------
// GRU recurrence. One block of 512 threads (8 waves, 2/SIMD) per batch elem.
// Thread (g = tid>>3, s = tid&7) owns k-sixteenth [16s,16s+16) of rows
// g+64m, m=0..5  ->  96 weight VGPRs (guaranteed VGPR-resident, no AGPR).
// 3-stage all-DPP reduction over s; every lane ends with all 6 full dots ->
// gates computed redundantly (wave-level cost identical), s==0 writes h.
// h stored as 8 chunks of 16 dwords at stride 20: the 8 wave-level b128
// address groups cover all 32 banks exactly once (conflict-free).
// ---------------------------------------------------------------------------
#define HCH(c) (20 * ((c) >> 4) + ((c) & 15))   // LDS dword addr of h column c

#define GRU_STEP(CUR, NXT, TLOAD, PB)                                          \
  {                                                                            \
    const float* gn_ = gib + (size_t)(TLOAD) * S;                              \
    _Pragma("unroll")                                                          \
    for (int m = 0; m < 6; m++) NXT[m] = gn_[g + 64 * m];                      \
    const float4* hp_ = reinterpret_cast<const float4*>(&h_sh[PB][20 * s]);    \
    float a_[6] = {0.f, 0.f, 0.f, 0.f, 0.f, 0.f};                              \
    _Pragma("unroll")                                                          \
    for (int i = 0; i < 4; i++) {                                              \
      float4 hv = hp_[i];                                                      \
      _Pragma("unroll")                                                        \
      for (int m = 0; m < 6; m++) a_[m] = fmaf(w4[m][i].x, hv.x, a_[m]);       \
      _Pragma("unroll")                                                        \
      for (int m = 0; m < 6; m++) a_[m] = fmaf(w4[m][i].y, hv.y, a_[m]);       \
      _Pragma("unroll")                                                        \
      for (int m = 0; m < 6; m++) a_[m] = fmaf(w4[m][i].z, hv.z, a_[m]);       \
      _Pragma("unroll")                                                        \
      for (int m = 0; m < 6; m++) a_[m] = fmaf(w4[m][i].w, hv.w, a_[m]);       \
    }                                                                          \
    _Pragma("unroll")                                                          \
    for (int m = 0; m < 6; m++) {                                              \
      a_[m] = dpp_add_xor1(a_[m]);                                             \
      a_[m] = dpp_add_xor2(a_[m]);                                             \
      a_[m] = dpp_add_hmirror(a_[m]);                                          \
    }                                                                          \
    const float r0 = sigmoid_(CUR[0] + a_[0]);                                 \
    const float r1 = sigmoid_(CUR[1] + a_[1]);                                 \
    const float z0 = sigmoid_(CUR[2] + a_[2]);                                 \
    const float z1 = sigmoid_(CUR[3] + a_[3]);                                 \
    const float n0 = tanh_(CUR[4] + r0 * (a_[4] + bh4));                       \
    const float n1 = tanh_(CUR[5] + r1 * (a_[5] + bh5));                       \
    hj0 = (1.f - z0) * n0 + z0 * hj0;                                          \
    hj1 = (1.f - z1) * n1 + z1 * hj1;                                          \
    hs0 += hj0; hs1 += hj1;                                                    \
    if (s == 0) {                                                              \
      h_sh[(PB) ^ 1][HCH(g)]      = hj0;                                       \
      h_sh[(PB) ^ 1][HCH(g + 64)] = hj1;                                       \
    }                                                                          \
    __syncthreads();                                                           \
  }

__global__ __launch_bounds__(512, 1)
void rec_kernel(const float* __restrict__ gi, const float* __restrict__ w_hh,
                const float* __restrict__ b_hh,
                const float* __restrict__ w_proj, const float* __restrict__ b_proj,
                float* __restrict__ out, float* __restrict__ state,
                int t0, int t1)
{
    const int tid = threadIdx.x;
    const int b = blockIdx.x;
    const int g = tid >> 3;     // 0..63
    const int s = tid & 7;      // k-sixteenth
    const int nT = t1 - t0;     // multiple of 128 -> even

    __shared__ float h_sh[2][160];   // 8 chunks of 16 dwords, stride 20
    __shared__ float pooled[HID_];

    float4 w4[6][4];
    #pragma unroll
    for (int m = 0; m < 6; m++) {
        const float* wr = w_hh + (size_t)(g + 64 * m) * HID_ + 16 * s;
        #pragma unroll
        for (int i = 0; i < 4; i++) w4[m][i] = reinterpret_cast<const float4*>(wr)[i];
    }
    const float bh4 = b_hh[256 + g];
    const float bh5 = b_hh[320 + g];

    float hj0, hj1, hs0, hs1;
    if (t0 == 0) { hj0 = hj1 = hs0 = hs1 = 0.f; }
    else {
        hj0 = state[b * HID_ + g];             hj1 = state[b * HID_ + g + 64];
        hs0 = state[B_ * HID_ + b * HID_ + g]; hs1 = state[B_ * HID_ + b * HID_ + g + 64];
    }
    if (tid < HID_) {
        float v = (t0 == 0) ? 0.f : state[b * HID_ + tid];
        h_sh[0][HCH(tid)] = v;
    }
    __syncthreads();

    const float* gib = gi + (size_t)b * G3_;
    const size_t S = (size_t)B_ * G3_;

    float cur[6], nxt[6];
    #pragma unroll
    for (int m = 0; m < 6; m++) cur[m] = gib[g + 64 * m];

    for (int t = 0; t < nT; t += 2) {
        GRU_STEP(cur, nxt, t + 1, 0);                         // t+1 < nT (nT even)
        const int tl2 = (t + 2 < nT) ? t + 2 : nT - 1;        // clamped; unused if last
        GRU_STEP(nxt, cur, tl2, 1);
    }

    if (t1 < T_) {
        if (s == 0) {
            state[b * HID_ + g]             = hj0;  state[b * HID_ + g + 64]             = hj1;
            state[B_ * HID_ + b * HID_ + g] = hs0;  state[B_ * HID_ + b * HID_ + g + 64] = hs1;
        }
    } else {
        if (s == 0) {
            pooled[g]      = hs0 * (1.f / (float)T_);
            pooled[g + 64] = hs1 * (1.f / (float)T_);
        }
        __syncthreads();
        if (tid < E_) {
            const float4* wp = reinterpret_cast<const float4*>(w_proj + (size_t)tid * HID_);
            const float4* pp = reinterpret_cast<const float4*>(pooled);
            float a0 = 0.f, a1 = 0.f, a2 = 0.f, a3 = 0.f;
            #pragma unroll
            for (int k = 0; k < 32; k++) {
                float4 wv = wp[k]; float4 pv = pp[k];
                a0 = fmaf(wv.x, pv.x, a0);
                a1 = fmaf(wv.y, pv.y, a1);
                a2 = fmaf(wv.z, pv.z, a2);
                a3 = fmaf(wv.w, pv.w, a3);
            }
            out[b * E_ + tid] = (a0 + a1) + (a2 + a3) + b_proj[tid];
        }
    }
}

extern "C" void kernel_launch(void* const* d_in, const int* in_sizes, int n_in,
                              void* d_out, int out_size, void* d_ws, size_t ws_size,
                              hipStream_t stream)
{
    const float* x      = (const float*)d_in[0];
    const float* w_ih   = (const float*)d_in[1];
    const float* w_hh   = (const float*)d_in[2];
    const float* b_ih   = (const float*)d_in[3];
    const float* b_hh   = (const float*)d_in[4];
    const float* w_proj = (const float*)d_in[5];
    const float* b_proj = (const float*)d_in[6];
    float* out = (float*)d_out;

    // ws layout: [ gi chunk buffer: chunkT * B * 3H * f32 ][ state: h + hsum ]
    const size_t state_bytes = (size_t)2 * B_ * HID_ * sizeof(float);
    const size_t per_t = (size_t)B_ * G3_ * sizeof(float);
    size_t avail = ws_size > state_bytes ? ws_size - state_bytes : 0;
    int chunkT = (int)(avail / per_t);
    if (chunkT > T_) chunkT = T_;
    chunkT &= ~(TS_ - 1);
    if (chunkT < TS_) chunkT = TS_;

    float* gi_buf = (float*)d_ws;
    float* state  = (float*)((char*)d_ws + (size_t)chunkT * per_t);

    for (int t0 = 0; t0 < T_; t0 += chunkT) {
        int t1 = t0 + chunkT; if (t1 > T_) t1 = T_;
        int nT = t1 - t0;
        gi_gemm<<<dim3(3, nT / TS_, B_), dim3(256), 0, stream>>>(x, w_ih, b_ih, b_hh, gi_buf, t0);
        rec_kernel<<<dim3(B_), dim3(512), 0, stream>>>(gi_buf, w_hh, b_hh, w_proj, b_proj,
                                                       out, state, t0, t1);
    }
}

// Round 5
// 1319.547 us; speedup vs baseline: 4.3995x; 1.0922x over previous
//
#include <hip/hip_runtime.h>
#include <math.h>

#define B_   64
#define T_   2048
#define HID_ 128
#define G3_  384   // 3*HID
#define IN_  128
#define E_   64

#define TS_  128   // t-tile of gi GEMM
#define GS_  128   // g-tile
#define KS_  32    // K stage

typedef _Float16 h2f __attribute__((ext_vector_type(2)));

__device__ __forceinline__ float rcp_(float x)     { return __builtin_amdgcn_rcpf(x); }
__device__ __forceinline__ float sigmoid_(float x) { return rcp_(1.f + __expf(-x)); }
__device__ __forceinline__ float tanh_(float x)    { return 1.f - 2.f * rcp_(1.f + __expf(2.f * x)); }

#if defined(__has_builtin)
#if __has_builtin(__builtin_amdgcn_fdot2)
#define FDOT2(a, b, c) __builtin_amdgcn_fdot2((a), (b), (c), false)
#endif
#endif
#ifndef FDOT2
#define FDOT2(a, b, c) ((c) + (float)(a)[0] * (float)(b)[0] + (float)(a)[1] * (float)(b)[1])
#endif

// DPP reduction over the 8-lane s-group (8-aligned lanes): xor1, xor2
// (quad_perm), then row_half_mirror (s <-> 7-s) -> full 8-lane sum everywhere.
__device__ __forceinline__ float dpp_add_xor1(float x) {
    int v = __builtin_amdgcn_mov_dpp(__float_as_int(x), 0xB1, 0xF, 0xF, true); // [1,0,3,2]
    return x + __int_as_float(v);
}
__device__ __forceinline__ float dpp_add_xor2(float x) {
    int v = __builtin_amdgcn_mov_dpp(__float_as_int(x), 0x4E, 0xF, 0xF, true); // [2,3,0,1]
    return x + __int_as_float(v);
}
__device__ __forceinline__ float dpp_add_hmirror(float x) {
    int v = __builtin_amdgcn_mov_dpp(__float_as_int(x), 0x141, 0xF, 0xF, true); // row_half_mirror
    return x + __int_as_float(v);
}

// ---------------------------------------------------------------------------
// gi GEMM: gi[tl][b][g] = x[b][t0+tl][:] . w_ih[g][:] + bias[g]
// bias folds b_hh for the r,z gates (additive pre-sigmoid).
// ---------------------------------------------------------------------------
__global__ __launch_bounds__(256)
void gi_gemm(const float* __restrict__ x, const float* __restrict__ w_ih,
             const float* __restrict__ b_ih, const float* __restrict__ b_hh,
             float* __restrict__ gi, int t0)
{
    __shared__ float Ash[KS_][TS_];   // [k][t]
    __shared__ float Bsh[KS_][GS_];   // [k][g]

    const int tid = threadIdx.x;
    const int gt  = blockIdx.x;
    const int tt  = blockIdx.y;
    const int b   = blockIdx.z;
    const int gbase  = gt * GS_;
    const int tlocal = tt * TS_;
    const int tabs   = t0 + tlocal;

    const int tx = tid & 15;
    const int ty = tid >> 4;

    const float* xrow = x    + ((size_t)b * T_ + tabs) * IN_;
    const float* wrow = w_ih + (size_t)gbase * IN_;

    float acc[8][8];
    #pragma unroll
    for (int i = 0; i < 8; i++)
        #pragma unroll
        for (int j = 0; j < 8; j++) acc[i][j] = 0.f;

    for (int ks = 0; ks < IN_; ks += KS_) {
        __syncthreads();
        #pragma unroll
        for (int i = 0; i < 4; i++) {
            const int idx = tid + i * 256;
            const int r   = idx >> 3;
            const int kg  = idx & 7;
            float4 av = *reinterpret_cast<const float4*>(xrow + (size_t)r * IN_ + ks + kg * 4);
            Ash[kg * 4 + 0][r] = av.x;
            Ash[kg * 4 + 1][r] = av.y;
            Ash[kg * 4 + 2][r] = av.z;
            Ash[kg * 4 + 3][r] = av.w;
            float4 bv = *reinterpret_cast<const float4*>(wrow + (size_t)r * IN_ + ks + kg * 4);
            Bsh[kg * 4 + 0][r] = bv.x;
            Bsh[kg * 4 + 1][r] = bv.y;
            Bsh[kg * 4 + 2][r] = bv.z;
            Bsh[kg * 4 + 3][r] = bv.w;
        }
        __syncthreads();

        #pragma unroll
        for (int k = 0; k < KS_; k++) {
            float4 a0 = *reinterpret_cast<const float4*>(&Ash[k][ty * 8]);
            float4 a1 = *reinterpret_cast<const float4*>(&Ash[k][ty * 8 + 4]);
            float4 b0 = *reinterpret_cast<const float4*>(&Bsh[k][tx * 4]);
            float4 b1 = *reinterpret_cast<const float4*>(&Bsh[k][64 + tx * 4]);
            const float av[8] = {a0.x,a0.y,a0.z,a0.w,a1.x,a1.y,a1.z,a1.w};
            const float bv[8] = {b0.x,b0.y,b0.z,b0.w,b1.x,b1.y,b1.z,b1.w};
            #pragma unroll
            for (int i = 0; i < 8; i++)
                #pragma unroll
                for (int j = 0; j < 8; j++)
                    acc[i][j] = fmaf(av[i], bv[j], acc[i][j]);
        }
    }

    float bi[8];
    #pragma unroll
    for (int c = 0; c < 4; c++) {
        const int col0 = gbase + tx * 4 + c;
        const int col1 = gbase + 64 + tx * 4 + c;
        bi[c]     = b_ih[col0] + (col0 < 256 ? b_hh[col0] : 0.f);
        bi[4 + c] = b_ih[col1] + (col1 < 256 ? b_hh[col1] : 0.f);
    }

    #pragma unroll
    for (int i = 0; i < 8; i++) {
        const size_t o = (size_t)(tlocal + ty * 8 + i) * (B_ * G3_) + (size_t)b * G3_ + gbase;
        float4 v0 = { acc[i][0] + bi[0], acc[i][1] + bi[1], acc[i][2] + bi[2], acc[i][3] + bi[3] };
        float4 v1 = { acc[i][4] + bi[4], acc[i][5] + bi[5], acc[i][6] + bi[6], acc[i][7] + bi[7] };
        *reinterpret_cast<float4*>(gi + o + tx * 4)      = v0;
        *reinterpret_cast<float4*>(gi + o + 64 + tx * 4) = v1;
    }
}

// ---------------------------------------------------------------------------
// GRU recurrence, f16-dot2 core. One block of 512 threads (8 waves) per b.
// Thread (g = tid>>3, s = tid&7) owns ADJACENT h columns 2g, 2g+1 and the
// k-chunk [16s,16s+16) of their six gate rows (2g+c+128m), held as 48 packed
// half2 VGPRs. h lives in LDS as packed f16 pairs (64 dwords/buffer);
// 2x ds_read_b128 per thread per step (2-way bank aliasing only -> free).
// Partial dots reduce over s via 3-stage all-DPP butterfly. hj/hsum carry in
// f32 registers -> only the W.h product sees f16 rounding.
// ---------------------------------------------------------------------------
#define GRU_STEP(CUR, NXT, TLOAD, PB)                                          \
  {                                                                            \
    const float* gn_ = gib + (size_t)(TLOAD) * S;                              \
    {                                                                          \
      const float2 g0_ = *reinterpret_cast<const float2*>(gn_ + 2 * g);        \
      const float2 g1_ = *reinterpret_cast<const float2*>(gn_ + 128 + 2 * g);  \
      const float2 g2_ = *reinterpret_cast<const float2*>(gn_ + 256 + 2 * g);  \
      NXT[0] = g0_.x; NXT[1] = g0_.y; NXT[2] = g1_.x;                          \
      NXT[3] = g1_.y; NXT[4] = g2_.x; NXT[5] = g2_.y;                          \
    }                                                                          \
    const uint4* hp_ = reinterpret_cast<const uint4*>(&h2_sh[PB][8 * s]);      \
    const uint4 u0_ = hp_[0];                                                  \
    const uint4 u1_ = hp_[1];                                                  \
    const unsigned hw_[8] = {u0_.x, u0_.y, u0_.z, u0_.w,                       \
                             u1_.x, u1_.y, u1_.z, u1_.w};                      \
    float a_[6] = {0.f, 0.f, 0.f, 0.f, 0.f, 0.f};                              \
    _Pragma("unroll")                                                          \
    for (int j = 0; j < 8; j++) {                                              \
      const h2f hv_ = __builtin_bit_cast(h2f, hw_[j]);                         \
      _Pragma("unroll")                                                        \
      for (int m = 0; m < 6; m++) a_[m] = FDOT2(wp[m][j], hv_, a_[m]);         \
    }                                                                          \
    _Pragma("unroll")                                                          \
    for (int m = 0; m < 6; m++) {                                              \
      a_[m] = dpp_add_xor1(a_[m]);                                             \
      a_[m] = dpp_add_xor2(a_[m]);                                             \
      a_[m] = dpp_add_hmirror(a_[m]);                                          \
    }                                                                          \
    const float r0 = sigmoid_(CUR[0] + a_[0]);                                 \
    const float r1 = sigmoid_(CUR[1] + a_[1]);                                 \
    const float z0 = sigmoid_(CUR[2] + a_[2]);                                 \
    const float z1 = sigmoid_(CUR[3] + a_[3]);                                 \
    const float n0 = tanh_(CUR[4] + r0 * (a_[4] + bh0));                       \
    const float n1 = tanh_(CUR[5] + r1 * (a_[5] + bh1));                       \
    hj0 = (1.f - z0) * n0 + z0 * hj0;                                          \
    hj1 = (1.f - z1) * n1 + z1 * hj1;                                          \
    hs0 += hj0; hs1 += hj1;                                                    \
    if (s == 0)                                                                \
      h2_sh[(PB) ^ 1][g] =                                                     \
          __builtin_bit_cast(unsigned, __builtin_amdgcn_cvt_pkrtz(hj0, hj1));  \
    __syncthreads();                                                           \
  }

__global__ __launch_bounds__(512, 1)
void rec_kernel(const float* __restrict__ gi, const float* __restrict__ w_hh,
                const float* __restrict__ b_hh,
                const float* __restrict__ w_proj, const float* __restrict__ b_proj,
                float* __restrict__ out, float* __restrict__ state,
                int t0, int t1)
{
    const int tid = threadIdx.x;
    const int b = blockIdx.x;
    const int g = tid >> 3;     // 0..63 -> h columns 2g, 2g+1
    const int s = tid & 7;      // k-sixteenth [16s, 16s+16)
    const int nT = t1 - t0;     // multiple of 128 -> even

    __shared__ unsigned h2_sh[2][64];   // h as packed f16 pairs
    __shared__ float pooled[HID_];

    // 48 packed weight registers: wp[2m+c][j] = (w[2g+c+128m][16s+2j], ...+2j+1)
    h2f wp[6][8];
    #pragma unroll
    for (int m = 0; m < 3; m++) {
        #pragma unroll
        for (int c = 0; c < 2; c++) {
            const float* wr = w_hh + (size_t)(2 * g + c + 128 * m) * HID_ + 16 * s;
            #pragma unroll
            for (int j = 0; j < 8; j++) {
                h2f v;
                v[0] = (_Float16)wr[2 * j];
                v[1] = (_Float16)wr[2 * j + 1];
                wp[2 * m + c][j] = v;
            }
        }
    }
    const float bh0 = b_hh[256 + 2 * g];
    const float bh1 = b_hh[257 + 2 * g];

    float hj0, hj1, hs0, hs1;
    if (t0 == 0) { hj0 = hj1 = hs0 = hs1 = 0.f; }
    else {
        hj0 = state[b * HID_ + 2 * g];             hj1 = state[b * HID_ + 2 * g + 1];
        hs0 = state[B_ * HID_ + b * HID_ + 2 * g]; hs1 = state[B_ * HID_ + b * HID_ + 2 * g + 1];
    }
    if (s == 0)
        h2_sh[0][g] = __builtin_bit_cast(unsigned, __builtin_amdgcn_cvt_pkrtz(hj0, hj1));
    __syncthreads();

    const float* gib = gi + (size_t)b * G3_;
    const size_t S = (size_t)B_ * G3_;

    float cur[6], nxt[6];
    {
        const float2 g0_ = *reinterpret_cast<const float2*>(gib + 2 * g);
        const float2 g1_ = *reinterpret_cast<const float2*>(gib + 128 + 2 * g);
        const float2 g2_ = *reinterpret_cast<const float2*>(gib + 256 + 2 * g);
        cur[0] = g0_.x; cur[1] = g0_.y; cur[2] = g1_.x;
        cur[3] = g1_.y; cur[4] = g2_.x; cur[5] = g2_.y;
    }

    for (int t = 0; t < nT; t += 2) {
        GRU_STEP(cur, nxt, t + 1, 0);                         // t+1 < nT (nT even)
        const int tl2 = (t + 2 < nT) ? t + 2 : nT - 1;        // clamped; unused if last
        GRU_STEP(nxt, cur, tl2, 1);
    }

    if (t1 < T_) {
        if (s == 0) {
            state[b * HID_ + 2 * g]                 = hj0;
            state[b * HID_ + 2 * g + 1]             = hj1;
            state[B_ * HID_ + b * HID_ + 2 * g]     = hs0;
            state[B_ * HID_ + b * HID_ + 2 * g + 1] = hs1;
        }
    } else {
        if (s == 0) {
            pooled[2 * g]     = hs0 * (1.f / (float)T_);
            pooled[2 * g + 1] = hs1 * (1.f / (float)T_);
        }
        __syncthreads();
        if (tid < E_) {
            const float4* wpj = reinterpret_cast<const float4*>(w_proj + (size_t)tid * HID_);
            const float4* pp  = reinterpret_cast<const float4*>(pooled);
            float a0 = 0.f, a1 = 0.f, a2 = 0.f, a3 = 0.f;
            #pragma unroll
            for (int k = 0; k < 32; k++) {
                float4 wv = wpj[k]; float4 pv = pp[k];
                a0 = fmaf(wv.x, pv.x, a0);
                a1 = fmaf(wv.y, pv.y, a1);
                a2 = fmaf(wv.z, pv.z, a2);
                a3 = fmaf(wv.w, pv.w, a3);
            }
            out[b * E_ + tid] = (a0 + a1) + (a2 + a3) + b_proj[tid];
        }
    }
}

extern "C" void kernel_launch(void* const* d_in, const int* in_sizes, int n_in,
                              void* d_out, int out_size, void* d_ws, size_t ws_size,
                              hipStream_t stream)
{
    const float* x      = (const float*)d_in[0];
    const float* w_ih   = (const float*)d_in[1];
    const float* w_hh   = (const float*)d_in[2];
    const float* b_ih   = (const float*)d_in[3];
    const float* b_hh   = (const float*)d_in[4];
    const float* w_proj = (const float*)d_in[5];
    const float* b_proj = (const float*)d_in[6];
    float* out = (float*)d_out;

    // ws layout: [ gi chunk buffer: chunkT * B * 3H * f32 ][ state: h + hsum ]
    const size_t state_bytes = (size_t)2 * B_ * HID_ * sizeof(float);
    const size_t per_t = (size_t)B_ * G3_ * sizeof(float);
    size_t avail = ws_size > state_bytes ? ws_size - state_bytes : 0;
    int chunkT = (int)(avail / per_t);
    if (chunkT > T_) chunkT = T_;
    chunkT &= ~(TS_ - 1);
    if (chunkT < TS_) chunkT = TS_;

    float* gi_buf = (float*)d_ws;
    float* state  = (float*)((char*)d_ws + (size_t)chunkT * per_t);

    for (int t0 = 0; t0 < T_; t0 += chunkT) {
        int t1 = t0 + chunkT; if (t1 > T_) t1 = T_;
        int nT = t1 - t0;
        gi_gemm<<<dim3(3, nT / TS_, B_), dim3(256), 0, stream>>>(x, w_ih, b_ih, b_hh, gi_buf, t0);
        rec_kernel<<<dim3(B_), dim3(512), 0, stream>>>(gi_buf, w_hh, b_hh, w_proj, b_proj,
                                                       out, state, t0, t1);
    }
}

// Round 6
// 1065.034 us; speedup vs baseline: 5.4509x; 1.2390x over previous
//
#include <hip/hip_runtime.h>
#include <math.h>

#define B_   64
#define T_   2048
#define HID_ 128
#define G3_  384   // 3*HID
#define IN_  128
#define E_   64

#define TS_  128   // t-tile of gi GEMM
#define GS_  128   // g-tile
#define KS_  32    // K stage

typedef _Float16 h2f __attribute__((ext_vector_type(2)));

__device__ __forceinline__ float rcp_(float x)     { return __builtin_amdgcn_rcpf(x); }
__device__ __forceinline__ float sigmoid_(float x) { return rcp_(1.f + __expf(-x)); }
__device__ __forceinline__ float tanh_(float x)    { return 1.f - 2.f * rcp_(1.f + __expf(2.f * x)); }

#if defined(__has_builtin)
#if __has_builtin(__builtin_amdgcn_fdot2)
#define FDOT2(a, b, c) __builtin_amdgcn_fdot2((a), (b), (c), false)
#endif
#endif
#ifndef FDOT2
#define FDOT2(a, b, c) ((c) + (float)(a)[0] * (float)(b)[0] + (float)(a)[1] * (float)(b)[1])
#endif

// DPP reduction over the 4-lane s-group (4-aligned quads): xor1 then xor2.
__device__ __forceinline__ float dpp_add_xor1(float x) {
    int v = __builtin_amdgcn_mov_dpp(__float_as_int(x), 0xB1, 0xF, 0xF, true); // [1,0,3,2]
    return x + __int_as_float(v);
}
__device__ __forceinline__ float dpp_add_xor2(float x) {
    int v = __builtin_amdgcn_mov_dpp(__float_as_int(x), 0x4E, 0xF, 0xF, true); // [2,3,0,1]
    return x + __int_as_float(v);
}

// ---------------------------------------------------------------------------
// gi GEMM: gi[tl][b][g] = x[b][t0+tl][:] . w_ih[g][:] + bias[g]
// bias folds b_hh for the r,z gates (additive pre-sigmoid).
// ---------------------------------------------------------------------------
__global__ __launch_bounds__(256)
void gi_gemm(const float* __restrict__ x, const float* __restrict__ w_ih,
             const float* __restrict__ b_ih, const float* __restrict__ b_hh,
             float* __restrict__ gi, int t0)
{
    __shared__ float Ash[KS_][TS_];   // [k][t]
    __shared__ float Bsh[KS_][GS_];   // [k][g]

    const int tid = threadIdx.x;
    const int gt  = blockIdx.x;
    const int tt  = blockIdx.y;
    const int b   = blockIdx.z;
    const int gbase  = gt * GS_;
    const int tlocal = tt * TS_;
    const int tabs   = t0 + tlocal;

    const int tx = tid & 15;
    const int ty = tid >> 4;

    const float* xrow = x    + ((size_t)b * T_ + tabs) * IN_;
    const float* wrow = w_ih + (size_t)gbase * IN_;

    float acc[8][8];
    #pragma unroll
    for (int i = 0; i < 8; i++)
        #pragma unroll
        for (int j = 0; j < 8; j++) acc[i][j] = 0.f;

    for (int ks = 0; ks < IN_; ks += KS_) {
        __syncthreads();
        #pragma unroll
        for (int i = 0; i < 4; i++) {
            const int idx = tid + i * 256;
            const int r   = idx >> 3;
            const int kg  = idx & 7;
            float4 av = *reinterpret_cast<const float4*>(xrow + (size_t)r * IN_ + ks + kg * 4);
            Ash[kg * 4 + 0][r] = av.x;
            Ash[kg * 4 + 1][r] = av.y;
            Ash[kg * 4 + 2][r] = av.z;
            Ash[kg * 4 + 3][r] = av.w;
            float4 bv = *reinterpret_cast<const float4*>(wrow + (size_t)r * IN_ + ks + kg * 4);
            Bsh[kg * 4 + 0][r] = bv.x;
            Bsh[kg * 4 + 1][r] = bv.y;
            Bsh[kg * 4 + 2][r] = bv.z;
            Bsh[kg * 4 + 3][r] = bv.w;
        }
        __syncthreads();

        #pragma unroll
        for (int k = 0; k < KS_; k++) {
            float4 a0 = *reinterpret_cast<const float4*>(&Ash[k][ty * 8]);
            float4 a1 = *reinterpret_cast<const float4*>(&Ash[k][ty * 8 + 4]);
            float4 b0 = *reinterpret_cast<const float4*>(&Bsh[k][tx * 4]);
            float4 b1 = *reinterpret_cast<const float4*>(&Bsh[k][64 + tx * 4]);
            const float av[8] = {a0.x,a0.y,a0.z,a0.w,a1.x,a1.y,a1.z,a1.w};
            const float bv[8] = {b0.x,b0.y,b0.z,b0.w,b1.x,b1.y,b1.z,b1.w};
            #pragma unroll
            for (int i = 0; i < 8; i++)
                #pragma unroll
                for (int j = 0; j < 8; j++)
                    acc[i][j] = fmaf(av[i], bv[j], acc[i][j]);
        }
    }

    float bi[8];
    #pragma unroll
    for (int c = 0; c < 4; c++) {
        const int col0 = gbase + tx * 4 + c;
        const int col1 = gbase + 64 + tx * 4 + c;
        bi[c]     = b_ih[col0] + (col0 < 256 ? b_hh[col0] : 0.f);
        bi[4 + c] = b_ih[col1] + (col1 < 256 ? b_hh[col1] : 0.f);
    }

    #pragma unroll
    for (int i = 0; i < 8; i++) {
        const size_t o = (size_t)(tlocal + ty * 8 + i) * (B_ * G3_) + (size_t)b * G3_ + gbase;
        float4 v0 = { acc[i][0] + bi[0], acc[i][1] + bi[1], acc[i][2] + bi[2], acc[i][3] + bi[3] };
        float4 v1 = { acc[i][4] + bi[4], acc[i][5] + bi[5], acc[i][6] + bi[6], acc[i][7] + bi[7] };
        *reinterpret_cast<float4*>(gi + o + tx * 4)      = v0;
        *reinterpret_cast<float4*>(gi + o + 64 + tx * 4) = v1;
    }
}

// ---------------------------------------------------------------------------
// GRU recurrence, f16-dot2 core. One block of 256 threads (4 waves, exactly
// 1 per SIMD) per batch element -- minimizes issue contention on the per-step
// critical path (this problem is latency-bound: wall time = T * L).
// Thread (g = tid>>2, s = tid&3) owns ADJACENT h columns 2g, 2g+1 and the
// k-chunk [32s,32s+32) of their six gate rows (2g+c+128m), held as 96 packed
// half2 VGPRs (fits the 256-VGPR cap at 1 wave/SIMD -> no AGPR shuttling).
// h lives in LDS as packed f16 pairs; 4x ds_read_b128 per thread per step
// (2-way bank aliasing only -> free). Partial dots reduce over s via 2-stage
// quad-DPP butterfly. hj/hsum carry in f32 -> only W.h sees f16 rounding.
// ---------------------------------------------------------------------------
#define GRU_STEP(CUR, NXT, TLOAD, PB)                                          \
  {                                                                            \
    const float* gn_ = gib + (size_t)(TLOAD) * S;                              \
    {                                                                          \
      const float2 g0_ = *reinterpret_cast<const float2*>(gn_ + 2 * g);        \
      const float2 g1_ = *reinterpret_cast<const float2*>(gn_ + 128 + 2 * g);  \
      const float2 g2_ = *reinterpret_cast<const float2*>(gn_ + 256 + 2 * g);  \
      NXT[0] = g0_.x; NXT[1] = g0_.y; NXT[2] = g1_.x;                          \
      NXT[3] = g1_.y; NXT[4] = g2_.x; NXT[5] = g2_.y;                          \
    }                                                                          \
    const uint4* hp_ = reinterpret_cast<const uint4*>(&h2_sh[PB][16 * s]);     \
    const uint4 u0_ = hp_[0];                                                  \
    const uint4 u1_ = hp_[1];                                                  \
    const uint4 u2_ = hp_[2];                                                  \
    const uint4 u3_ = hp_[3];                                                  \
    const unsigned hw_[16] = {u0_.x, u0_.y, u0_.z, u0_.w,                      \
                              u1_.x, u1_.y, u1_.z, u1_.w,                      \
                              u2_.x, u2_.y, u2_.z, u2_.w,                      \
                              u3_.x, u3_.y, u3_.z, u3_.w};                     \
    float a_[6] = {0.f, 0.f, 0.f, 0.f, 0.f, 0.f};                              \
    _Pragma("unroll")                                                          \
    for (int j = 0; j < 16; j++) {                                             \
      const h2f hv_ = __builtin_bit_cast(h2f, hw_[j]);                         \
      _Pragma("unroll")                                                        \
      for (int m = 0; m < 6; m++) a_[m] = FDOT2(wp[m][j], hv_, a_[m]);         \
    }                                                                          \
    _Pragma("unroll")                                                          \
    for (int m = 0; m < 6; m++) {                                              \
      a_[m] = dpp_add_xor1(a_[m]);                                             \
      a_[m] = dpp_add_xor2(a_[m]);                                             \
    }                                                                          \
    const float r0 = sigmoid_(CUR[0] + a_[0]);                                 \
    const float r1 = sigmoid_(CUR[1] + a_[1]);                                 \
    const float z0 = sigmoid_(CUR[2] + a_[2]);                                 \
    const float z1 = sigmoid_(CUR[3] + a_[3]);                                 \
    const float n0 = tanh_(CUR[4] + r0 * (a_[4] + bh0));                       \
    const float n1 = tanh_(CUR[5] + r1 * (a_[5] + bh1));                       \
    hj0 = (1.f - z0) * n0 + z0 * hj0;                                          \
    hj1 = (1.f - z1) * n1 + z1 * hj1;                                          \
    hs0 += hj0; hs1 += hj1;                                                    \
    if (s == 0)                                                                \
      h2_sh[(PB) ^ 1][g] =                                                     \
          __builtin_bit_cast(unsigned, __builtin_amdgcn_cvt_pkrtz(hj0, hj1));  \
    __syncthreads();                                                           \
  }

__global__ __launch_bounds__(256, 1)
void rec_kernel(const float* __restrict__ gi, const float* __restrict__ w_hh,
                const float* __restrict__ b_hh,
                const float* __restrict__ w_proj, const float* __restrict__ b_proj,
                float* __restrict__ out, float* __restrict__ state,
                int t0, int t1)
{
    const int tid = threadIdx.x;
    const int b = blockIdx.x;
    const int g = tid >> 2;     // 0..63 -> h columns 2g, 2g+1
    const int s = tid & 3;      // k-chunk [32s, 32s+32)
    const int nT = t1 - t0;     // multiple of 128 -> even

    __shared__ unsigned h2_sh[2][64];   // h as packed f16 pairs
    __shared__ float pooled[HID_];

    // 96 packed weight registers: wp[2m+c][j] = (w[2g+c+128m][32s+2j], ...+2j+1)
    h2f wp[6][16];
    #pragma unroll
    for (int m = 0; m < 3; m++) {
        #pragma unroll
        for (int c = 0; c < 2; c++) {
            const float* wr = w_hh + (size_t)(2 * g + c + 128 * m) * HID_ + 32 * s;
            #pragma unroll
            for (int j = 0; j < 16; j++) {
                h2f v;
                v[0] = (_Float16)wr[2 * j];
                v[1] = (_Float16)wr[2 * j + 1];
                wp[2 * m + c][j] = v;
            }
        }
    }
    const float bh0 = b_hh[256 + 2 * g];
    const float bh1 = b_hh[257 + 2 * g];

    float hj0, hj1, hs0, hs1;
    if (t0 == 0) { hj0 = hj1 = hs0 = hs1 = 0.f; }
    else {
        hj0 = state[b * HID_ + 2 * g];             hj1 = state[b * HID_ + 2 * g + 1];
        hs0 = state[B_ * HID_ + b * HID_ + 2 * g]; hs1 = state[B_ * HID_ + b * HID_ + 2 * g + 1];
    }
    if (s == 0)
        h2_sh[0][g] = __builtin_bit_cast(unsigned, __builtin_amdgcn_cvt_pkrtz(hj0, hj1));
    __syncthreads();

    const float* gib = gi + (size_t)b * G3_;
    const size_t S = (size_t)B_ * G3_;

    float cur[6], nxt[6];
    {
        const float2 g0_ = *reinterpret_cast<const float2*>(gib + 2 * g);
        const float2 g1_ = *reinterpret_cast<const float2*>(gib + 128 + 2 * g);
        const float2 g2_ = *reinterpret_cast<const float2*>(gib + 256 + 2 * g);
        cur[0] = g0_.x; cur[1] = g0_.y; cur[2] = g1_.x;
        cur[3] = g1_.y; cur[4] = g2_.x; cur[5] = g2_.y;
    }

    for (int t = 0; t < nT; t += 2) {
        GRU_STEP(cur, nxt, t + 1, 0);                         // t+1 < nT (nT even)
        const int tl2 = (t + 2 < nT) ? t + 2 : nT - 1;        // clamped; unused if last
        GRU_STEP(nxt, cur, tl2, 1);
    }

    if (t1 < T_) {
        if (s == 0) {
            state[b * HID_ + 2 * g]                 = hj0;
            state[b * HID_ + 2 * g + 1]             = hj1;
            state[B_ * HID_ + b * HID_ + 2 * g]     = hs0;
            state[B_ * HID_ + b * HID_ + 2 * g + 1] = hs1;
        }
    } else {
        if (s == 0) {
            pooled[2 * g]     = hs0 * (1.f / (float)T_);
            pooled[2 * g + 1] = hs1 * (1.f / (float)T_);
        }
        __syncthreads();
        if (tid < E_) {
            const float4* wpj = reinterpret_cast<const float4*>(w_proj + (size_t)tid * HID_);
            const float4* pp  = reinterpret_cast<const float4*>(pooled);
            float a0 = 0.f, a1 = 0.f, a2 = 0.f, a3 = 0.f;
            #pragma unroll
            for (int k = 0; k < 32; k++) {
                float4 wv = wpj[k]; float4 pv = pp[k];
                a0 = fmaf(wv.x, pv.x, a0);
                a1 = fmaf(wv.y, pv.y, a1);
                a2 = fmaf(wv.z, pv.z, a2);
                a3 = fmaf(wv.w, pv.w, a3);
            }
            out[b * E_ + tid] = (a0 + a1) + (a2 + a3) + b_proj[tid];
        }
    }
}

extern "C" void kernel_launch(void* const* d_in, const int* in_sizes, int n_in,
                              void* d_out, int out_size, void* d_ws, size_t ws_size,
                              hipStream_t stream)
{
    const float* x      = (const float*)d_in[0];
    const float* w_ih   = (const float*)d_in[1];
    const float* w_hh   = (const float*)d_in[2];
    const float* b_ih   = (const float*)d_in[3];
    const float* b_hh   = (const float*)d_in[4];
    const float* w_proj = (const float*)d_in[5];
    const float* b_proj = (const float*)d_in[6];
    float* out = (float*)d_out;

    // ws layout: [ gi chunk buffer: chunkT * B * 3H * f32 ][ state: h + hsum ]
    const size_t state_bytes = (size_t)2 * B_ * HID_ * sizeof(float);
    const size_t per_t = (size_t)B_ * G3_ * sizeof(float);
    size_t avail = ws_size > state_bytes ? ws_size - state_bytes : 0;
    int chunkT = (int)(avail / per_t);
    if (chunkT > T_) chunkT = T_;
    chunkT &= ~(TS_ - 1);
    if (chunkT < TS_) chunkT = TS_;

    float* gi_buf = (float*)d_ws;
    float* state  = (float*)((char*)d_ws + (size_t)chunkT * per_t);

    for (int t0 = 0; t0 < T_; t0 += chunkT) {
        int t1 = t0 + chunkT; if (t1 > T_) t1 = T_;
        int nT = t1 - t0;
        gi_gemm<<<dim3(3, nT / TS_, B_), dim3(256), 0, stream>>>(x, w_ih, b_ih, b_hh, gi_buf, t0);
        rec_kernel<<<dim3(B_), dim3(256), 0, stream>>>(gi_buf, w_hh, b_hh, w_proj, b_proj,
                                                       out, state, t0, t1);
    }
}

// Round 7
// 1046.506 us; speedup vs baseline: 5.5474x; 1.0177x over previous
//
#include <hip/hip_runtime.h>
#include <math.h>

#define B_   64
#define T_   2048
#define HID_ 128
#define G3_  384   // 3*HID
#define IN_  128
#define E_   64

#define TS_  128   // t-tile of gi GEMM block

typedef _Float16 h2f  __attribute__((ext_vector_type(2)));
typedef _Float16 f16x8 __attribute__((ext_vector_type(8)));
typedef float    f32x4 __attribute__((ext_vector_type(4)));

__device__ __forceinline__ float rcp_(float x)     { return __builtin_amdgcn_rcpf(x); }
__device__ __forceinline__ float sigmoid_(float x) { return rcp_(1.f + __expf(-x)); }
__device__ __forceinline__ float tanh_(float x)    { return 1.f - 2.f * rcp_(1.f + __expf(2.f * x)); }

#if defined(__has_builtin)
#if __has_builtin(__builtin_amdgcn_fdot2)
#define FDOT2(a, b, c) __builtin_amdgcn_fdot2((a), (b), (c), false)
#endif
#endif
#ifndef FDOT2
#define FDOT2(a, b, c) ((c) + (float)(a)[0] * (float)(b)[0] + (float)(a)[1] * (float)(b)[1])
#endif

// DPP reduction over the 4-lane s-group (4-aligned quads): xor1 then xor2.
__device__ __forceinline__ float dpp_add_xor1(float x) {
    int v = __builtin_amdgcn_mov_dpp(__float_as_int(x), 0xB1, 0xF, 0xF, true); // [1,0,3,2]
    return x + __int_as_float(v);
}
__device__ __forceinline__ float dpp_add_xor2(float x) {
    int v = __builtin_amdgcn_mov_dpp(__float_as_int(x), 0x4E, 0xF, 0xF, true); // [2,3,0,1]
    return x + __int_as_float(v);
}

// pack 8 f32 -> f16x8 via 4x cvt_pkrtz
__device__ __forceinline__ f16x8 pack8_(float4 a, float4 b) {
    uint4 u;
    u.x = __builtin_bit_cast(unsigned, __builtin_amdgcn_cvt_pkrtz(a.x, a.y));
    u.y = __builtin_bit_cast(unsigned, __builtin_amdgcn_cvt_pkrtz(a.z, a.w));
    u.z = __builtin_bit_cast(unsigned, __builtin_amdgcn_cvt_pkrtz(b.x, b.y));
    u.w = __builtin_bit_cast(unsigned, __builtin_amdgcn_cvt_pkrtz(b.z, b.w));
    return __builtin_bit_cast(f16x8, u);
}

// ---------------------------------------------------------------------------
// gi GEMM, f16 MFMA: gi[tl][b][g] = x[b][t0+tl][:] . w_ih[g][:] + bias[g]
// bias folds b_hh for the r,z gates (additive pre-sigmoid).
// Block = (128 t-rows) x (all 384 g), 256 threads. Wave w owns t-rows
// [32w,32w+32) as 2 M-tiles x 24 N-tiles, K=128 as 4 chunks of 32.
// mfma_f32_16x16x32_f16; fragments loaded straight from global (w_ih is
// L2-resident; x region contiguous), packed to f16 via cvt_pkrtz.
// A/B frag: elem[m or n = lane&15][k=(lane>>4)*8+j]; C/D: col=lane&15,
// row=(lane>>4)*4+reg  (m89/m120-verified layouts, dtype-independent).
// Memory floor: 64MB x-read + 201MB gi-write ~ 42us.
// ---------------------------------------------------------------------------
__global__ __launch_bounds__(256, 1)
void gi_gemm(const float* __restrict__ x, const float* __restrict__ w_ih,
             const float* __restrict__ b_ih, const float* __restrict__ b_hh,
             float* __restrict__ gi, int t0)
{
    const int tid = threadIdx.x;
    const int w   = tid >> 6;          // wave 0..3
    const int l   = tid & 63;          // lane
    const int ln  = l & 15;            // A-row / B-row / C-col within tile
    const int kq  = l >> 4;            // k-quad (0..3)
    const int tt  = blockIdx.x;        // t-tile (128 rows) within chunk
    const int b   = blockIdx.y;        // batch
    const int tl_base = tt * TS_ + w * 32;   // chunk-relative t of this wave

    // per-lane bias for each N-tile (C-col = nt*16 + ln)
    float bias_r[24];
    #pragma unroll
    for (int nt = 0; nt < 24; nt++) {
        const int col = nt * 16 + ln;
        bias_r[nt] = b_ih[col] + (col < 256 ? b_hh[col] : 0.f);
    }

    f32x4 acc[2][24];
    #pragma unroll
    for (int mt = 0; mt < 2; mt++)
        #pragma unroll
        for (int nt = 0; nt < 24; nt++)
            acc[mt][nt] = (f32x4){0.f, 0.f, 0.f, 0.f};

    const float* xb = x + ((size_t)b * T_ + (size_t)(t0 + tl_base)) * IN_;

    #pragma unroll
    for (int kc = 0; kc < 4; kc++) {
        const int ko = kc * 32 + kq * 8;
        f16x8 afr[2];
        #pragma unroll
        for (int mt = 0; mt < 2; mt++) {
            const float* xr = xb + (size_t)(mt * 16 + ln) * IN_ + ko;
            float4 p0 = *reinterpret_cast<const float4*>(xr);
            float4 p1 = *reinterpret_cast<const float4*>(xr + 4);
            afr[mt] = pack8_(p0, p1);
        }
        #pragma unroll
        for (int nt = 0; nt < 24; nt++) {
            const float* wr = w_ih + (size_t)(nt * 16 + ln) * IN_ + ko;
            float4 q0 = *reinterpret_cast<const float4*>(wr);
            float4 q1 = *reinterpret_cast<const float4*>(wr + 4);
            const f16x8 bfr = pack8_(q0, q1);
            acc[0][nt] = __builtin_amdgcn_mfma_f32_16x16x32_f16(afr[0], bfr, acc[0][nt], 0, 0, 0);
            acc[1][nt] = __builtin_amdgcn_mfma_f32_16x16x32_f16(afr[1], bfr, acc[1][nt], 0, 0, 0);
        }
    }

    // store: C row = (l>>4)*4 + r (t-dim), col = ln (g-dim)
    #pragma unroll
    for (int mt = 0; mt < 2; mt++) {
        #pragma unroll
        for (int r = 0; r < 4; r++) {
            const size_t trow = (size_t)(tl_base + mt * 16 + kq * 4 + r);
            float* go = gi + trow * (B_ * G3_) + (size_t)b * G3_ + ln;
            #pragma unroll
            for (int nt = 0; nt < 24; nt++)
                go[nt * 16] = acc[mt][nt][r] + bias_r[nt];
        }
    }
}

// ---------------------------------------------------------------------------
// GRU recurrence, f16-dot2 core. One block of 256 threads (4 waves, exactly
// 1 per SIMD) per batch element -- minimizes issue contention on the per-step
// critical path (this problem is latency-bound: wall time = T * L).
// Thread (g = tid>>2, s = tid&3) owns ADJACENT h columns 2g, 2g+1 and the
// k-chunk [32s,32s+32) of their six gate rows (2g+c+128m), held as 96 packed
// half2 VGPRs. h lives in LDS as packed f16 pairs; 4x ds_read_b128 per thread
// per step (2-way bank aliasing only -> free). Partial dots reduce over s via
// 2-stage quad-DPP butterfly. hj/hsum carry in f32 -> only W.h sees f16
// rounding.  (unchanged from round 6)
// ---------------------------------------------------------------------------
#define GRU_STEP(CUR, NXT, TLOAD, PB)                                          \
  {                                                                            \
    const float* gn_ = gib + (size_t)(TLOAD) * S;                              \
    {                                                                          \
      const float2 g0_ = *reinterpret_cast<const float2*>(gn_ + 2 * g);        \
      const float2 g1_ = *reinterpret_cast<const float2*>(gn_ + 128 + 2 * g);  \
      const float2 g2_ = *reinterpret_cast<const float2*>(gn_ + 256 + 2 * g);  \
      NXT[0] = g0_.x; NXT[1] = g0_.y; NXT[2] = g1_.x;                          \
      NXT[3] = g1_.y; NXT[4] = g2_.x; NXT[5] = g2_.y;                          \
    }                                                                          \
    const uint4* hp_ = reinterpret_cast<const uint4*>(&h2_sh[PB][16 * s]);     \
    const uint4 u0_ = hp_[0];                                                  \
    const uint4 u1_ = hp_[1];                                                  \
    const uint4 u2_ = hp_[2];                                                  \
    const uint4 u3_ = hp_[3];                                                  \
    const unsigned hw_[16] = {u0_.x, u0_.y, u0_.z, u0_.w,                      \
                              u1_.x, u1_.y, u1_.z, u1_.w,                      \
                              u2_.x, u2_.y, u2_.z, u2_.w,                      \
                              u3_.x, u3_.y, u3_.z, u3_.w};                     \
    float a_[6] = {0.f, 0.f, 0.f, 0.f, 0.f, 0.f};                              \
    _Pragma("unroll")                                                          \
    for (int j = 0; j < 16; j++) {                                             \
      const h2f hv_ = __builtin_bit_cast(h2f, hw_[j]);                         \
      _Pragma("unroll")                                                        \
      for (int m = 0; m < 6; m++) a_[m] = FDOT2(wp[m][j], hv_, a_[m]);         \
    }                                                                          \
    _Pragma("unroll")                                                          \
    for (int m = 0; m < 6; m++) {                                              \
      a_[m] = dpp_add_xor1(a_[m]);                                             \
      a_[m] = dpp_add_xor2(a_[m]);                                             \
    }                                                                          \
    const float r0 = sigmoid_(CUR[0] + a_[0]);                                 \
    const float r1 = sigmoid_(CUR[1] + a_[1]);                                 \
    const float z0 = sigmoid_(CUR[2] + a_[2]);                                 \
    const float z1 = sigmoid_(CUR[3] + a_[3]);                                 \
    const float n0 = tanh_(CUR[4] + r0 * (a_[4] + bh0));                       \
    const float n1 = tanh_(CUR[5] + r1 * (a_[5] + bh1));                       \
    hj0 = (1.f - z0) * n0 + z0 * hj0;                                          \
    hj1 = (1.f - z1) * n1 + z1 * hj1;                                          \
    hs0 += hj0; hs1 += hj1;                                                    \
    if (s == 0)                                                                \
      h2_sh[(PB) ^ 1][g] =                                                     \
          __builtin_bit_cast(unsigned, __builtin_amdgcn_cvt_pkrtz(hj0, hj1));  \
    __syncthreads();                                                           \
  }

__global__ __launch_bounds__(256, 1)
void rec_kernel(const float* __restrict__ gi, const float* __restrict__ w_hh,
                const float* __restrict__ b_hh,
                const float* __restrict__ w_proj, const float* __restrict__ b_proj,
                float* __restrict__ out, float* __restrict__ state,
                int t0, int t1)
{
    const int tid = threadIdx.x;
    const int b = blockIdx.x;
    const int g = tid >> 2;     // 0..63 -> h columns 2g, 2g+1
    const int s = tid & 3;      // k-chunk [32s, 32s+32)
    const int nT = t1 - t0;     // multiple of 128 -> even

    __shared__ unsigned h2_sh[2][64];   // h as packed f16 pairs
    __shared__ float pooled[HID_];

    // 96 packed weight registers: wp[2m+c][j] = (w[2g+c+128m][32s+2j], ...+2j+1)
    h2f wp[6][16];
    #pragma unroll
    for (int m = 0; m < 3; m++) {
        #pragma unroll
        for (int c = 0; c < 2; c++) {
            const float* wr = w_hh + (size_t)(2 * g + c + 128 * m) * HID_ + 32 * s;
            #pragma unroll
            for (int j = 0; j < 16; j++) {
                h2f v;
                v[0] = (_Float16)wr[2 * j];
                v[1] = (_Float16)wr[2 * j + 1];
                wp[2 * m + c][j] = v;
            }
        }
    }
    const float bh0 = b_hh[256 + 2 * g];
    const float bh1 = b_hh[257 + 2 * g];

    float hj0, hj1, hs0, hs1;
    if (t0 == 0) { hj0 = hj1 = hs0 = hs1 = 0.f; }
    else {
        hj0 = state[b * HID_ + 2 * g];             hj1 = state[b * HID_ + 2 * g + 1];
        hs0 = state[B_ * HID_ + b * HID_ + 2 * g]; hs1 = state[B_ * HID_ + b * HID_ + 2 * g + 1];
    }
    if (s == 0)
        h2_sh[0][g] = __builtin_bit_cast(unsigned, __builtin_amdgcn_cvt_pkrtz(hj0, hj1));
    __syncthreads();

    const float* gib = gi + (size_t)b * G3_;
    const size_t S = (size_t)B_ * G3_;

    float cur[6], nxt[6];
    {
        const float2 g0_ = *reinterpret_cast<const float2*>(gib + 2 * g);
        const float2 g1_ = *reinterpret_cast<const float2*>(gib + 128 + 2 * g);
        const float2 g2_ = *reinterpret_cast<const float2*>(gib + 256 + 2 * g);
        cur[0] = g0_.x; cur[1] = g0_.y; cur[2] = g1_.x;
        cur[3] = g1_.y; cur[4] = g2_.x; cur[5] = g2_.y;
    }

    for (int t = 0; t < nT; t += 2) {
        GRU_STEP(cur, nxt, t + 1, 0);                         // t+1 < nT (nT even)
        const int tl2 = (t + 2 < nT) ? t + 2 : nT - 1;        // clamped; unused if last
        GRU_STEP(nxt, cur, tl2, 1);
    }

    if (t1 < T_) {
        if (s == 0) {
            state[b * HID_ + 2 * g]                 = hj0;
            state[b * HID_ + 2 * g + 1]             = hj1;
            state[B_ * HID_ + b * HID_ + 2 * g]     = hs0;
            state[B_ * HID_ + b * HID_ + 2 * g + 1] = hs1;
        }
    } else {
        if (s == 0) {
            pooled[2 * g]     = hs0 * (1.f / (float)T_);
            pooled[2 * g + 1] = hs1 * (1.f / (float)T_);
        }
        __syncthreads();
        if (tid < E_) {
            const float4* wpj = reinterpret_cast<const float4*>(w_proj + (size_t)tid * HID_);
            const float4* pp  = reinterpret_cast<const float4*>(pooled);
            float a0 = 0.f, a1 = 0.f, a2 = 0.f, a3 = 0.f;
            #pragma unroll
            for (int k = 0; k < 32; k++) {
                float4 wv = wpj[k]; float4 pv = pp[k];
                a0 = fmaf(wv.x, pv.x, a0);
                a1 = fmaf(wv.y, pv.y, a1);
                a2 = fmaf(wv.z, pv.z, a2);
                a3 = fmaf(wv.w, pv.w, a3);
            }
            out[b * E_ + tid] = (a0 + a1) + (a2 + a3) + b_proj[tid];
        }
    }
}

extern "C" void kernel_launch(void* const* d_in, const int* in_sizes, int n_in,
                              void* d_out, int out_size, void* d_ws, size_t ws_size,
                              hipStream_t stream)
{
    const float* x      = (const float*)d_in[0];
    const float* w_ih   = (const float*)d_in[1];
    const float* w_hh   = (const float*)d_in[2];
    const float* b_ih   = (const float*)d_in[3];
    const float* b_hh   = (const float*)d_in[4];
    const float* w_proj = (const float*)d_in[5];
    const float* b_proj = (const float*)d_in[6];
    float* out = (float*)d_out;

    // ws layout: [ gi chunk buffer: chunkT * B * 3H * f32 ][ state: h + hsum ]
    const size_t state_bytes = (size_t)2 * B_ * HID_ * sizeof(float);
    const size_t per_t = (size_t)B_ * G3_ * sizeof(float);
    size_t avail = ws_size > state_bytes ? ws_size - state_bytes : 0;
    int chunkT = (int)(avail / per_t);
    if (chunkT > T_) chunkT = T_;
    chunkT &= ~(TS_ - 1);
    if (chunkT < TS_) chunkT = TS_;

    float* gi_buf = (float*)d_ws;
    float* state  = (float*)((char*)d_ws + (size_t)chunkT * per_t);

    for (int t0 = 0; t0 < T_; t0 += chunkT) {
        int t1 = t0 + chunkT; if (t1 > T_) t1 = T_;
        int nT = t1 - t0;
        gi_gemm<<<dim3(nT / TS_, B_), dim3(256), 0, stream>>>(x, w_ih, b_ih, b_hh, gi_buf, t0);
        rec_kernel<<<dim3(B_), dim3(256), 0, stream>>>(gi_buf, w_hh, b_hh, w_proj, b_proj,
                                                       out, state, t0, t1);
    }
}

// Round 8
// 987.020 us; speedup vs baseline: 5.8817x; 1.0603x over previous
//
#include <hip/hip_runtime.h>
#include <math.h>

#define B_   64
#define T_   2048
#define HID_ 128
#define G3_  384   // 3*HID
#define IN_  128
#define E_   64

#define TS_  128   // t-tile of gi GEMM block

typedef _Float16 h2f  __attribute__((ext_vector_type(2)));
typedef _Float16 f16x8 __attribute__((ext_vector_type(8)));
typedef float    f32x4 __attribute__((ext_vector_type(4)));

__device__ __forceinline__ float rcp_(float x)     { return __builtin_amdgcn_rcpf(x); }
__device__ __forceinline__ float sigmoid_(float x) { return rcp_(1.f + __expf(-x)); }
__device__ __forceinline__ float tanh_(float x)    { return 1.f - 2.f * rcp_(1.f + __expf(2.f * x)); }

// pack 8 f32 -> f16x8 via 4x cvt_pkrtz
__device__ __forceinline__ f16x8 pack8_(float4 a, float4 b) {
    uint4 u;
    u.x = __builtin_bit_cast(unsigned, __builtin_amdgcn_cvt_pkrtz(a.x, a.y));
    u.y = __builtin_bit_cast(unsigned, __builtin_amdgcn_cvt_pkrtz(a.z, a.w));
    u.z = __builtin_bit_cast(unsigned, __builtin_amdgcn_cvt_pkrtz(b.x, b.y));
    u.w = __builtin_bit_cast(unsigned, __builtin_amdgcn_cvt_pkrtz(b.z, b.w));
    return __builtin_bit_cast(f16x8, u);
}

// ---------------------------------------------------------------------------
// gi GEMM, f16 MFMA (unchanged from round 7).
// ---------------------------------------------------------------------------
__global__ __launch_bounds__(256, 1)
void gi_gemm(const float* __restrict__ x, const float* __restrict__ w_ih,
             const float* __restrict__ b_ih, const float* __restrict__ b_hh,
             float* __restrict__ gi, int t0)
{
    const int tid = threadIdx.x;
    const int w   = tid >> 6;
    const int l   = tid & 63;
    const int ln  = l & 15;
    const int kq  = l >> 4;
    const int tt  = blockIdx.x;
    const int b   = blockIdx.y;
    const int tl_base = tt * TS_ + w * 32;

    float bias_r[24];
    #pragma unroll
    for (int nt = 0; nt < 24; nt++) {
        const int col = nt * 16 + ln;
        bias_r[nt] = b_ih[col] + (col < 256 ? b_hh[col] : 0.f);
    }

    f32x4 acc[2][24];
    #pragma unroll
    for (int mt = 0; mt < 2; mt++)
        #pragma unroll
        for (int nt = 0; nt < 24; nt++)
            acc[mt][nt] = (f32x4){0.f, 0.f, 0.f, 0.f};

    const float* xb = x + ((size_t)b * T_ + (size_t)(t0 + tl_base)) * IN_;

    #pragma unroll
    for (int kc = 0; kc < 4; kc++) {
        const int ko = kc * 32 + kq * 8;
        f16x8 afr[2];
        #pragma unroll
        for (int mt = 0; mt < 2; mt++) {
            const float* xr = xb + (size_t)(mt * 16 + ln) * IN_ + ko;
            float4 p0 = *reinterpret_cast<const float4*>(xr);
            float4 p1 = *reinterpret_cast<const float4*>(xr + 4);
            afr[mt] = pack8_(p0, p1);
        }
        #pragma unroll
        for (int nt = 0; nt < 24; nt++) {
            const float* wr = w_ih + (size_t)(nt * 16 + ln) * IN_ + ko;
            float4 q0 = *reinterpret_cast<const float4*>(wr);
            float4 q1 = *reinterpret_cast<const float4*>(wr + 4);
            const f16x8 bfr = pack8_(q0, q1);
            acc[0][nt] = __builtin_amdgcn_mfma_f32_16x16x32_f16(afr[0], bfr, acc[0][nt], 0, 0, 0);
            acc[1][nt] = __builtin_amdgcn_mfma_f32_16x16x32_f16(afr[1], bfr, acc[1][nt], 0, 0, 0);
        }
    }

    #pragma unroll
    for (int mt = 0; mt < 2; mt++) {
        #pragma unroll
        for (int r = 0; r < 4; r++) {
            const size_t trow = (size_t)(tl_base + mt * 16 + kq * 4 + r);
            float* go = gi + trow * (B_ * G3_) + (size_t)b * G3_ + ln;
            #pragma unroll
            for (int nt = 0; nt < 24; nt++)
                go[nt * 16] = acc[mt][nt][r] + bias_r[nt];
        }
    }
}

// ---------------------------------------------------------------------------
// GRU recurrence, MFMA core with replicated-A trick. One block of 256
// threads (4 waves, 1/SIMD) per batch element (64 blocks).
// A-frag A[m=ln][k] = h[k] (lane-independent -> broadcast ds_read_b128 of
// packed-f16 h). B-frags = w_hh rows c0+64m (c0 = 16w+ln), m=0..5, packed
// f16x8 x 4 k-chunks = 96 loop-invariant regs; MFMA reads A/B from VGPR or
// AGPR natively, so allocator placement cannot add shuttle cost.
// C/D (session-verified in gi_gemm): col=ln -> gate row c0+64m; rows are
// replicated copies -> use reg[0]. VALU per step: only gates (2 triplets,
// 12 transcendentals) + 6 gi loads. gi prefetched 2 steps ahead (ring-4).
// ---------------------------------------------------------------------------
#define REC_STEP(CUR, LD, TLOAD, PB)                                           \
  {                                                                            \
    const float* gp_ = gib + (size_t)(TLOAD) * S;                              \
    LD[0] = gp_[c0];       LD[1] = gp_[c0 + 64];                               \
    LD[2] = gp_[c0 + 128]; LD[3] = gp_[c0 + 192];                              \
    LD[4] = gp_[c0 + 256]; LD[5] = gp_[c0 + 320];                              \
    const char* hb_ = (const char*)(&h2_sh[PB][0]) + kq * 16;                  \
    f16x8 af_[4];                                                              \
    af_[0] = __builtin_bit_cast(f16x8, *(const uint4*)(hb_));                  \
    af_[1] = __builtin_bit_cast(f16x8, *(const uint4*)(hb_ + 64));             \
    af_[2] = __builtin_bit_cast(f16x8, *(const uint4*)(hb_ + 128));            \
    af_[3] = __builtin_bit_cast(f16x8, *(const uint4*)(hb_ + 192));            \
    f32x4 ac_[6];                                                              \
    _Pragma("unroll")                                                          \
    for (int m = 0; m < 6; m++) ac_[m] = (f32x4){0.f, 0.f, 0.f, 0.f};          \
    _Pragma("unroll")                                                          \
    for (int kc = 0; kc < 4; kc++) {                                           \
      _Pragma("unroll")                                                        \
      for (int m = 0; m < 6; m++)                                              \
        ac_[m] = __builtin_amdgcn_mfma_f32_16x16x32_f16(af_[kc], wfr[m][kc],   \
                                                        ac_[m], 0, 0, 0);      \
    }                                                                          \
    const float r0 = sigmoid_(CUR[0] + ac_[0][0]);                             \
    const float r1 = sigmoid_(CUR[1] + ac_[1][0]);                             \
    const float z0 = sigmoid_(CUR[2] + ac_[2][0]);                             \
    const float z1 = sigmoid_(CUR[3] + ac_[3][0]);                             \
    const float n0 = tanh_(CUR[4] + r0 * (ac_[4][0] + bh0));                   \
    const float n1 = tanh_(CUR[5] + r1 * (ac_[5][0] + bh1));                   \
    hj0 = (1.f - z0) * n0 + z0 * hj0;                                          \
    hj1 = (1.f - z1) * n1 + z1 * hj1;                                          \
    hs0 += hj0; hs1 += hj1;                                                    \
    if (kq == 0) {                                                             \
      h2_sh[(PB) ^ 1][c0] = (_Float16)hj0;                                     \
      h2_sh[(PB) ^ 1][c1] = (_Float16)hj1;                                     \
    }                                                                          \
    __syncthreads();                                                           \
  }

__global__ __launch_bounds__(256, 1)
void rec_kernel(const float* __restrict__ gi, const float* __restrict__ w_hh,
                const float* __restrict__ b_hh,
                const float* __restrict__ w_proj, const float* __restrict__ b_proj,
                float* __restrict__ out, float* __restrict__ state,
                int t0, int t1)
{
    const int tid  = threadIdx.x;
    const int b    = blockIdx.x;
    const int w    = tid >> 6;     // wave 0..3
    const int lane = tid & 63;
    const int ln   = lane & 15;
    const int kq   = lane >> 4;
    const int c0   = 16 * w + ln;  // h-col family 0 (family 1 = c0+64)
    const int c1   = c0 + 64;
    const int nT   = t1 - t0;      // multiple of 128 -> multiple of 4

    __shared__ _Float16 h2_sh[2][HID_];   // h as f16, double-buffered
    __shared__ float pooled[HID_];

    // B-frags: wfr[m][kc] = packed w_hh[c0+64m][kc*32+kq*8 .. +8)
    f16x8 wfr[6][4];
    #pragma unroll
    for (int m = 0; m < 6; m++) {
        const float* wr = w_hh + (size_t)(c0 + 64 * m) * HID_;
        #pragma unroll
        for (int kc = 0; kc < 4; kc++) {
            const float* p = wr + kc * 32 + kq * 8;
            float4 q0 = *reinterpret_cast<const float4*>(p);
            float4 q1 = *reinterpret_cast<const float4*>(p + 4);
            wfr[m][kc] = pack8_(q0, q1);
        }
    }
    const float bh0 = b_hh[256 + c0];
    const float bh1 = b_hh[256 + c1];

    float hj0, hj1, hs0, hs1;
    if (t0 == 0) { hj0 = hj1 = hs0 = hs1 = 0.f; }
    else {
        hj0 = state[b * HID_ + c0];             hj1 = state[b * HID_ + c1];
        hs0 = state[B_ * HID_ + b * HID_ + c0]; hs1 = state[B_ * HID_ + b * HID_ + c1];
    }
    if (kq == 0) {
        h2_sh[0][c0] = (_Float16)hj0;
        h2_sh[0][c1] = (_Float16)hj1;
    }
    __syncthreads();

    const float* gib = gi + (size_t)b * G3_;
    const size_t S = (size_t)B_ * G3_;

    // ring-4 gi buffers; prefetch depth 2 (L_step < HBM latency now)
    float g0[6], g1[6], g2[6], g3[6];
    {
        const float* p0 = gib;
        const float* p1 = gib + S;
        g0[0]=p0[c0]; g0[1]=p0[c0+64]; g0[2]=p0[c0+128]; g0[3]=p0[c0+192]; g0[4]=p0[c0+256]; g0[5]=p0[c0+320];
        g1[0]=p1[c0]; g1[1]=p1[c0+64]; g1[2]=p1[c0+128]; g1[3]=p1[c0+192]; g1[4]=p1[c0+256]; g1[5]=p1[c0+320];
    }

    int pb = 0;
    for (int t = 0; t < nT; t += 4) {
        const int nTm1 = nT - 1;
        int t2 = t + 2 < nTm1 ? t + 2 : nTm1;
        int t3 = t + 3 < nTm1 ? t + 3 : nTm1;
        int t4 = t + 4 < nTm1 ? t + 4 : nTm1;
        int t5 = t + 5 < nTm1 ? t + 5 : nTm1;
        REC_STEP(g0, g2, t2, pb); pb ^= 1;
        REC_STEP(g1, g3, t3, pb); pb ^= 1;
        REC_STEP(g2, g0, t4, pb); pb ^= 1;
        REC_STEP(g3, g1, t5, pb); pb ^= 1;
    }

    if (t1 < T_) {
        if (kq == 0) {
            state[b * HID_ + c0]             = hj0;  state[b * HID_ + c1]             = hj1;
            state[B_ * HID_ + b * HID_ + c0] = hs0;  state[B_ * HID_ + b * HID_ + c1] = hs1;
        }
    } else {
        if (kq == 0) {
            pooled[c0] = hs0 * (1.f / (float)T_);
            pooled[c1] = hs1 * (1.f / (float)T_);
        }
        __syncthreads();
        if (tid < E_) {
            const float4* wpj = reinterpret_cast<const float4*>(w_proj + (size_t)tid * HID_);
            const float4* pp  = reinterpret_cast<const float4*>(pooled);
            float a0 = 0.f, a1 = 0.f, a2 = 0.f, a3 = 0.f;
            #pragma unroll
            for (int k = 0; k < 32; k++) {
                float4 wv = wpj[k]; float4 pv = pp[k];
                a0 = fmaf(wv.x, pv.x, a0);
                a1 = fmaf(wv.y, pv.y, a1);
                a2 = fmaf(wv.z, pv.z, a2);
                a3 = fmaf(wv.w, pv.w, a3);
            }
            out[b * E_ + tid] = (a0 + a1) + (a2 + a3) + b_proj[tid];
        }
    }
}

extern "C" void kernel_launch(void* const* d_in, const int* in_sizes, int n_in,
                              void* d_out, int out_size, void* d_ws, size_t ws_size,
                              hipStream_t stream)
{
    const float* x      = (const float*)d_in[0];
    const float* w_ih   = (const float*)d_in[1];
    const float* w_hh   = (const float*)d_in[2];
    const float* b_ih   = (const float*)d_in[3];
    const float* b_hh   = (const float*)d_in[4];
    const float* w_proj = (const float*)d_in[5];
    const float* b_proj = (const float*)d_in[6];
    float* out = (float*)d_out;

    // ws layout: [ gi chunk buffer: chunkT * B * 3H * f32 ][ state: h + hsum ]
    const size_t state_bytes = (size_t)2 * B_ * HID_ * sizeof(float);
    const size_t per_t = (size_t)B_ * G3_ * sizeof(float);
    size_t avail = ws_size > state_bytes ? ws_size - state_bytes : 0;
    int chunkT = (int)(avail / per_t);
    if (chunkT > T_) chunkT = T_;
    chunkT &= ~(TS_ - 1);
    if (chunkT < TS_) chunkT = TS_;

    float* gi_buf = (float*)d_ws;
    float* state  = (float*)((char*)d_ws + (size_t)chunkT * per_t);

    for (int t0 = 0; t0 < T_; t0 += chunkT) {
        int t1 = t0 + chunkT; if (t1 > T_) t1 = T_;
        int nT = t1 - t0;
        gi_gemm<<<dim3(nT / TS_, B_), dim3(256), 0, stream>>>(x, w_ih, b_ih, b_hh, gi_buf, t0);
        rec_kernel<<<dim3(B_), dim3(256), 0, stream>>>(gi_buf, w_hh, b_hh, w_proj, b_proj,
                                                       out, state, t0, t1);
    }
}